// Round 16
// baseline (173.413 us; speedup 1.0000x reference)
//
#include <hip/hip_runtime.h>
#include <math.h>

#define BB 16
#define NL 4096
#define NH 1024
#define CL 128
#define CHH 256
#define K0 384
#define K1 256
#define CO 256
#define BN_EPS 1e-5f

typedef __attribute__((ext_vector_type(8))) short bfrag;     // 8 bf16
typedef __attribute__((ext_vector_type(4))) float f32x4;
typedef __attribute__((ext_vector_type(4))) unsigned short ushort4b;

__device__ inline unsigned short f2bf(float f) {
    unsigned int u = __builtin_bit_cast(unsigned int, f);
    u += 0x7fffu + ((u >> 16) & 1u);                 // RNE
    return (unsigned short)(u >> 16);
}
__device__ inline float bf2f(unsigned short h) {
    unsigned int u = ((unsigned int)h) << 16;
    return __builtin_bit_cast(float, u);
}

// async global->LDS, 16B per lane; LDS dest = wave-uniform base + lane*16
__device__ __forceinline__ void gl_lds16(const unsigned short* g, unsigned short* l) {
    __builtin_amdgcn_global_load_lds(
        (const __attribute__((address_space(1))) unsigned int*)(const void*)g,
        (__attribute__((address_space(3))) unsigned int*)(void*)l,
        16, 0, 0);
}

// ---------------------------------------------------------------------------
// setup: W0 split-repack (Wa = W0[:, :256] [m][256], Wlo = W0[:, 256:] [m][128]),
// W1 -> bf16, candidate packing. One launch.
// ---------------------------------------------------------------------------
__global__ __launch_bounds__(256) void k_setup(const float* __restrict__ W0s,
                                               unsigned short* __restrict__ Wa,
                                               unsigned short* __restrict__ Wlo,
                                               const float* __restrict__ W1s,
                                               unsigned short* __restrict__ Wb1,
                                               const float* __restrict__ xyzh,
                                               float4* __restrict__ cand4) {
    int i = blockIdx.x * 256 + threadIdx.x;
    if (i < CO * K0) {
        int m = i / K0, c = i - m * K0;
        unsigned short v = f2bf(W0s[i]);
        if (c < CHH) Wa[m * CHH + c] = v;
        else         Wlo[m * CL + (c - CHH)] = v;
    }
    if (i < CO * K1) Wb1[i] = f2bf(W1s[i]);
    if (i < BB * NH) {
        float x = xyzh[3 * i], y = xyzh[3 * i + 1], z = xyzh[3 * i + 2];
        float ss = __fadd_rn(__fadd_rn(__fmul_rn(x, x), __fmul_rn(y, y)),
                             __fmul_rn(z, z));
        cand4[i] = make_float4(x, y, z, ss);
    }
}

// ---------------------------------------------------------------------------
// transpose feat_high (B, CH, NH) f32 -> fT (B, NH, CH) bf16
// ---------------------------------------------------------------------------
__global__ __launch_bounds__(256) void k_transpose_fh(const float* __restrict__ fh,
                                                      unsigned short* __restrict__ fT) {
    __shared__ float s[32][33];
    int b = blockIdx.z;
    int c0 = blockIdx.y * 32;
    int m0 = blockIdx.x * 32;
    int tx = threadIdx.x % 32, ty = threadIdx.x / 32;
    const float* src = fh + (size_t)b * CHH * NH;
    unsigned short* dst = fT + (size_t)b * NH * CHH;
#pragma unroll
    for (int j = 0; j < 4; j++)
        s[ty + 8 * j][tx] = src[(size_t)(c0 + ty + 8 * j) * NH + m0 + tx];
    __syncthreads();
    int mi = threadIdx.x >> 3;
    int cp = threadIdx.x & 7;
#pragma unroll
    for (int h = 0; h < 2; h++) {
        int ci = (cp + 8 * h) * 2;
        unsigned int o = (unsigned int)f2bf(s[ci][mi]) |
                         ((unsigned int)f2bf(s[ci + 1][mi]) << 16);
        *(unsigned int*)&dst[(size_t)(m0 + mi) * CHH + c0 + ci] = o;
    }
}

// ---------------------------------------------------------------------------
// 3-NN search v7 (unchanged): wave = segment, broadcast LDS reads.
// ---------------------------------------------------------------------------
__global__ __launch_bounds__(256) void k_knn(const float* __restrict__ xyzl,
                                             const float4* __restrict__ cand4,
                                             int* __restrict__ idx,
                                             float* __restrict__ wgt) {
    __shared__ float4 cnd[NH];
    __shared__ float tls[4][64][3];
    __shared__ int   ils[4][64][3];

    int b = blockIdx.y;
    for (int p = threadIdx.x; p < NH; p += 256)
        cnd[p] = cand4[(size_t)b * NH + p];
    __syncthreads();

    int lane = threadIdx.x & 63;
    int w = threadIdx.x >> 6;
    int n = blockIdx.x * 64 + lane;

    const float* xl = xyzl + ((size_t)b * NL + n) * 3;
    float l0 = xl[0], l1 = xl[1], l2 = xl[2];
    float a = __fadd_rn(__fadd_rn(__fmul_rn(l0, l0), __fmul_rn(l1, l1)),
                        __fmul_rn(l2, l2));

    float t0 = INFINITY, t1 = INFINITY, t2 = INFINITY;
    int i0 = 0, i1 = 0, i2 = 0;
    int mb = w * 256;
#pragma unroll 8
    for (int j = 0; j < 256; j++) {
        float4 c = cnd[mb + j];
        int m = mb + j;
        float dot = __fadd_rn(__fadd_rn(__fmul_rn(l0, c.x), __fmul_rn(l1, c.y)),
                              __fmul_rn(l2, c.z));
        float dd = __fsub_rn(__fadd_rn(a, c.w), __fmul_rn(2.0f, dot));
        bool c0 = dd < t0, c1 = dd < t1, c2 = dd < t2;
        float nt0 = fminf(dd, t0);
        float nt1 = __builtin_amdgcn_fmed3f(dd, t0, t1);
        float nt2 = __builtin_amdgcn_fmed3f(dd, t1, t2);
        i2 = c1 ? i1 : (c2 ? m : i2);
        i1 = c0 ? i0 : (c1 ? m : i1);
        i0 = c0 ? m : i0;
        t0 = nt0; t1 = nt1; t2 = nt2;
    }
    tls[w][lane][0] = t0; tls[w][lane][1] = t1; tls[w][lane][2] = t2;
    ils[w][lane][0] = i0; ils[w][lane][1] = i1; ils[w][lane][2] = i2;
    __syncthreads();

    if (threadIdx.x < 64) {
        int p = threadIdx.x;
        float u0 = tls[0][p][0], u1 = tls[0][p][1], u2 = tls[0][p][2];
        int   j0 = ils[0][p][0], j1 = ils[0][p][1], j2 = ils[0][p][2];
#pragma unroll
        for (int sg = 1; sg < 4; sg++) {
#pragma unroll
            for (int e = 0; e < 3; e++) {
                float dd = tls[sg][p][e];
                int m = ils[sg][p][e];
                bool c0 = dd < u0, c1 = dd < u1, c2 = dd < u2;
                u2 = c1 ? u1 : (c2 ? dd : u2);
                j2 = c1 ? j1 : (c2 ? m : j2);
                u1 = c0 ? u0 : (c1 ? dd : u1);
                j1 = c0 ? j0 : (c1 ? m : j1);
                u0 = c0 ? dd : u0;
                j0 = c0 ? m : j0;
            }
        }
        u0 = fmaxf(u0, 0.0f); u1 = fmaxf(u1, 0.0f); u2 = fmaxf(u2, 0.0f);
        float d0 = sqrtf(u0), d1 = sqrtf(u1), d2 = sqrtf(u2);
        float w0 = 1.0f / fmaxf(d0, 1e-8f);
        float w1 = 1.0f / fmaxf(d1, 1e-8f);
        float w2 = 1.0f / fmaxf(d2, 1e-8f);
        float wsum = __fadd_rn(__fadd_rn(w0, w1), w2);
        w0 /= wsum; w1 /= wsum; w2 /= wsum;
        int nn = blockIdx.x * 64 + p;
        size_t base = ((size_t)b * NL + nn) * 3;
        idx[base] = j0; idx[base + 1] = j1; idx[base + 2] = j2;
        wgt[base] = w0; wgt[base + 1] = w1; wgt[base + 2] = w2;
    }
}

// ---------------------------------------------------------------------------
// feat_low (B, CL, NL) f32 -> Xb2[b][n][c] bf16, c in [0,128) (slim layout)
// ---------------------------------------------------------------------------
__global__ __launch_bounds__(256) void k_fl_t(const float* __restrict__ fl,
                                              unsigned short* __restrict__ Xb2) {
    __shared__ unsigned short s[32][68];
    int b = blockIdx.z, c0 = blockIdx.y * 32, n0 = blockIdx.x * 64;
    int tx = threadIdx.x & 63, ty = threadIdx.x >> 6;
    const float* src = fl + ((size_t)b * CL + c0) * NL + n0;
#pragma unroll
    for (int i = 0; i < 8; i++) {
        int c = ty * 8 + i;
        s[c][tx] = f2bf(src[(size_t)c * NL + tx]);
    }
    __syncthreads();
    int n = threadIdx.x >> 2, q = threadIdx.x & 3;
    ushort4b o0, o1;
#pragma unroll
    for (int e = 0; e < 4; e++) o0[e] = s[q * 8 + e][n];
#pragma unroll
    for (int e = 0; e < 4; e++) o1[e] = s[q * 8 + 4 + e][n];
    unsigned short* dst = Xb2 + ((size_t)b * NL + n0 + n) * CL + c0 + q * 8;
    *(ushort4b*)dst = o0;
    *(ushort4b*)(dst + 4) = o1;
}

// ---------------------------------------------------------------------------
// BN0+ReLU on an 8-elem bf16 fragment (bit-identical chain)
// ---------------------------------------------------------------------------
__device__ inline bfrag bnrelu8(bfrag v, f32x4 s0, f32x4 s1, f32x4 h0, f32x4 h1) {
    bfrag o;
#pragma unroll
    for (int e = 0; e < 4; e++)
        o[e] = (short)f2bf(fmaxf(fmaf(s0[e], bf2f((unsigned short)v[e]), h0[e]), 0.f));
#pragma unroll
    for (int e = 0; e < 4; e++)
        o[4 + e] = (short)f2bf(fmaxf(fmaf(s1[e], bf2f((unsigned short)v[4 + e]), h1[e]), 0.f));
    return o;
}

__device__ inline int swz(int r, int cb) {
    return r * 32 + ((cb ^ ((r >> 1) & 3)) << 3);   // short index, 16B blocks
}

// ---------------------------------------------------------------------------
// m97-style MFMA GEMM, parameterized:
// Y[b][n][m] = bf16( sum_k W[m][k]*X'[n][k] [+ bias] [+ sum_k w_k G[idx_k][m]] )
// 128x128 tile, BK=32, 4 waves, global_load_lds staging, XCD-paired grid
// of 2*NT*16 blocks (NT = n-tiles per batch). BN: relu(sc*x+sh) post-ds_read.
// GATHER: epilogue folds 3-NN weighted G rows (the interp@output trick).
// STATS: per-block per-channel partials to distinct slots.
// ---------------------------------------------------------------------------
#define EROW1 136   // epilogue LDS row stride in shorts

template <int K, int NT, bool BIASF, bool BN, bool GATHER, bool STATS>
__global__ __launch_bounds__(256) void k_gemm97(const unsigned short* __restrict__ X,
                                                const unsigned short* __restrict__ W,
                                                const float* __restrict__ bias,
                                                const float* __restrict__ bnsc,
                                                const float* __restrict__ bnsh,
                                                const unsigned short* __restrict__ G,
                                                const int* __restrict__ gidx,
                                                const float* __restrict__ gwgt,
                                                unsigned short* __restrict__ Y,
                                                float* __restrict__ psumT,
                                                float* __restrict__ psqT) {
    __shared__ __align__(16) unsigned short smem[4 * 4096];
    unsigned short* sA = smem;
    unsigned short* sB = smem + 2 * 4096;
    unsigned short* sE = smem;

    const int ROWS = NT * 128;
    int t = blockIdx.x;
    int xcd = t & 7, ii = t >> 3;
    int m0 = (ii & 1) * 128;
    int nb = ii >> 1;
    int n0 = (nb & (NT - 1)) * 128;
    int b  = xcd * 2 + (nb / NT);
    int slotbase = (xcd * 64 + (t >> 4)) * 2;

    int tid = threadIdx.x;
    int lane = tid & 63;
    int w = tid >> 6;
    int wm = w >> 1, wn = w & 1;

    int srow = w * 32 + (lane >> 2);
    int schunk = (lane & 3) ^ ((srow >> 1) & 3);
    const unsigned short* gA0 = W + (size_t)(m0 + srow) * K + schunk * 8;
    const unsigned short* gA1 = W + (size_t)(m0 + srow + 16) * K + schunk * 8;
    const unsigned short* gB0 = X + ((size_t)b * ROWS + n0 + srow) * K + schunk * 8;
    const unsigned short* gB1 = X + ((size_t)b * ROWS + n0 + srow + 16) * K + schunk * 8;
    unsigned short* lA0 = sA + (w * 32) * 32;
    unsigned short* lA1 = sA + (w * 32 + 16) * 32;
    unsigned short* lB0 = sB + (w * 32) * 32;
    unsigned short* lB1 = sB + (w * 32 + 16) * 32;

    f32x4 acc[4][4] = {};

    gl_lds16(gA0, lA0);
    gl_lds16(gA1, lA1);
    gl_lds16(gB0, lB0);
    gl_lds16(gB1, lB1);
    __syncthreads();

    const int nkt = K / 32;
    int cur = 0;
#pragma unroll 2
    for (int tt = 0; tt < nkt; tt++) {
        if (tt + 1 < nkt) {
            int kk = (tt + 1) * 32;
            int off = (cur ^ 1) * 4096;
            gl_lds16(gA0 + kk, lA0 + off);
            gl_lds16(gA1 + kk, lA1 + off);
            gl_lds16(gB0 + kk, lB0 + off);
            gl_lds16(gB1 + kk, lB1 + off);
        }
        bfrag af[4], bf[4];
#pragma unroll
        for (int mi = 0; mi < 4; mi++) {
            int r = wm * 64 + mi * 16 + (lane & 15);
            af[mi] = *(const bfrag*)&sA[cur * 4096 + swz(r, lane >> 4)];
        }
#pragma unroll
        for (int ni = 0; ni < 4; ni++) {
            int r = wn * 64 + ni * 16 + (lane & 15);
            bfrag raw = *(const bfrag*)&sB[cur * 4096 + swz(r, lane >> 4)];
            if (BN) {
                int cg = tt * 32 + (lane >> 4) * 8;
                f32x4 sc0 = *(const f32x4*)&bnsc[cg], sc1 = *(const f32x4*)&bnsc[cg + 4];
                f32x4 sh0 = *(const f32x4*)&bnsh[cg], sh1 = *(const f32x4*)&bnsh[cg + 4];
                bf[ni] = bnrelu8(raw, sc0, sc1, sh0, sh1);
            } else {
                bf[ni] = raw;
            }
        }
#pragma unroll
        for (int mi = 0; mi < 4; mi++)
#pragma unroll
            for (int ni = 0; ni < 4; ni++)
                acc[mi][ni] = __builtin_amdgcn_mfma_f32_16x16x32_bf16(
                    af[mi], bf[ni], acc[mi][ni], 0, 0, 0);
        __syncthreads();
        cur ^= 1;
    }

    int col = lane & 15, rg = (lane >> 4) << 2;

    // fold bias
    if (BIASF) {
#pragma unroll
        for (int mi = 0; mi < 4; mi++) {
            f32x4 bv = *(const f32x4*)&bias[m0 + wm * 64 + mi * 16 + rg];
#pragma unroll
            for (int ni = 0; ni < 4; ni++)
#pragma unroll
                for (int j = 0; j < 4; j++)
                    acc[mi][ni][j] += bv[j];
        }
    }

    // fold 3-NN weighted G rows (interp commuted past the conv)
    if (GATHER) {
#pragma unroll
        for (int ni = 0; ni < 4; ni++) {
            int n = n0 + wn * 64 + ni * 16 + col;
            size_t ib = ((size_t)b * NL + n) * 3;
            int g0 = gidx[ib], g1 = gidx[ib + 1], g2 = gidx[ib + 2];
            float w0 = gwgt[ib], w1 = gwgt[ib + 1], w2 = gwgt[ib + 2];
            const unsigned short* G0 = G + ((size_t)b * NH + g0) * CO;
            const unsigned short* G1 = G + ((size_t)b * NH + g1) * CO;
            const unsigned short* G2 = G + ((size_t)b * NH + g2) * CO;
#pragma unroll
            for (int mi = 0; mi < 4; mi++) {
                int m = m0 + wm * 64 + mi * 16 + rg;
                ushort4b v0 = *(const ushort4b*)&G0[m];
                ushort4b v1 = *(const ushort4b*)&G1[m];
                ushort4b v2 = *(const ushort4b*)&G2[m];
#pragma unroll
                for (int j = 0; j < 4; j++)
                    acc[mi][ni][j] += fmaf(w0, bf2f(v0[j]),
                                      fmaf(w1, bf2f(v1[j]),
                                           w2 * bf2f(v2[j])));
            }
        }
    }

    // stats (distinct slots, no atomics)
    if (STATS) {
#pragma unroll
        for (int mi = 0; mi < 4; mi++) {
            int m = m0 + wm * 64 + mi * 16 + rg;
            f32x4 sacc = {0.f, 0.f, 0.f, 0.f}, qacc = {0.f, 0.f, 0.f, 0.f};
#pragma unroll
            for (int ni = 0; ni < 4; ni++) {
                f32x4 c = acc[mi][ni];
#pragma unroll
                for (int j = 0; j < 4; j++) {
                    sacc[j] += c[j];
                    qacc[j] += c[j] * c[j];
                }
            }
#pragma unroll
            for (int j = 0; j < 4; j++) {
                float s = sacc[j], q = qacc[j];
#pragma unroll
                for (int off = 1; off < 16; off <<= 1) {
                    s += __shfl_xor(s, off, 64);
                    q += __shfl_xor(q, off, 64);
                }
                if (col == 0) {
                    psumT[(size_t)(m + j) * 1024 + slotbase + wn] = s;
                    psqT[(size_t)(m + j) * 1024 + slotbase + wn] = q;
                }
            }
        }
    }

    // two-half LDS transpose + coalesced Y store
#pragma unroll
    for (int half = 0; half < 2; half++) {
        if (wn == half) {
#pragma unroll
            for (int mi = 0; mi < 4; mi++) {
                int ml = wm * 64 + mi * 16 + rg;
#pragma unroll
                for (int ni = 0; ni < 4; ni++) {
                    int nloc = ni * 16 + col;
                    f32x4 c = acc[mi][ni];
                    ushort4b o;
                    o[0] = f2bf(c[0]); o[1] = f2bf(c[1]);
                    o[2] = f2bf(c[2]); o[3] = f2bf(c[3]);
                    *(ushort4b*)&sE[nloc * EROW1 + ml] = o;
                }
            }
        }
        __syncthreads();
#pragma unroll
        for (int s2 = 0; s2 < 4; s2++) {
            int row = s2 * 16 + (tid >> 4);
            int ch = tid & 15;
            *(bfrag*)&Y[((size_t)b * ROWS + n0 + half * 64 + row) * CO + m0 + ch * 8] =
                *(const bfrag*)&sE[row * EROW1 + ch * 8];
        }
        __syncthreads();
    }
}

// ---------------------------------------------------------------------------
// reduce per-block partials -> scale/shift. One block per channel.
// ---------------------------------------------------------------------------
__global__ __launch_bounds__(256) void k_fin(const float* __restrict__ psumT,
                                             const float* __restrict__ psqT,
                                             const float* __restrict__ gamma,
                                             const float* __restrict__ beta,
                                             float* __restrict__ scale,
                                             float* __restrict__ shift) {
    int c = blockIdx.x;
    const float* ps = psumT + (size_t)c * 1024;
    const float* pq = psqT + (size_t)c * 1024;
    float s = 0.f, q = 0.f;
    for (int i = threadIdx.x; i < 1024; i += 256) { s += ps[i]; q += pq[i]; }
#pragma unroll
    for (int off = 1; off < 64; off <<= 1) {
        s += __shfl_xor(s, off, 64);
        q += __shfl_xor(q, off, 64);
    }
    __shared__ float ls[4], lq[4];
    if ((threadIdx.x & 63) == 0) { ls[threadIdx.x >> 6] = s; lq[threadIdx.x >> 6] = q; }
    __syncthreads();
    if (threadIdx.x == 0) {
        float S = ls[0] + ls[1] + ls[2] + ls[3];
        float Q = lq[0] + lq[1] + lq[2] + lq[3];
        float N = (float)(BB * NL);
        float mean = S / N;
        float var = Q / N - mean * mean;
        float sc = gamma[c] / sqrtf(var + BN_EPS);
        scale[c] = sc;
        shift[c] = beta[c] - mean * sc;
    }
}

// ---------------------------------------------------------------------------
// final: read y1 bf16 [b][n][m], BN1+ReLU, transpose-write f32 out [b][m][n]
// ---------------------------------------------------------------------------
__global__ __launch_bounds__(256) void k_out(const unsigned short* __restrict__ y1,
                                             const float* __restrict__ scale,
                                             const float* __restrict__ shift,
                                             float* __restrict__ out) {
    __shared__ float s[64][65];
    int b = blockIdx.z, m0 = blockIdx.y * 64, n0 = blockIdx.x * 64;
    int r = threadIdx.x >> 3;
    int mq = (threadIdx.x & 7) * 8;
#pragma unroll
    for (int it = 0; it < 2; it++) {
        int row = r + it * 32;
        bfrag v = *(const bfrag*)&y1[((size_t)b * NL + n0 + row) * CO + m0 + mq];
#pragma unroll
        for (int e = 0; e < 8; e++) {
            int m = mq + e;
            float f = bf2f((unsigned short)v[e]);
            s[m][row] = fmaxf(fmaf(scale[m0 + m], f, shift[m0 + m]), 0.f);
        }
    }
    __syncthreads();
    int ch = threadIdx.x & 15;
    int mb4 = threadIdx.x >> 4;
#pragma unroll
    for (int it = 0; it < 4; it++) {
        int m = it * 16 + mb4;
        float4 v = make_float4(s[m][ch * 4], s[m][ch * 4 + 1],
                               s[m][ch * 4 + 2], s[m][ch * 4 + 3]);
        *(float4*)&out[((size_t)b * CO + m0 + m) * NL + n0 + ch * 4] = v;
    }
}

// ---------------------------------------------------------------------------
extern "C" void kernel_launch(void* const* d_in, const int* in_sizes, int n_in,
                              void* d_out, int out_size, void* d_ws, size_t ws_size,
                              hipStream_t stream) {
    const float* xyz_low   = (const float*)d_in[0];
    const float* xyz_high  = (const float*)d_in[1];
    const float* feat_low  = (const float*)d_in[2];
    const float* feat_high = (const float*)d_in[3];
    const float* W0  = (const float*)d_in[4];
    const float* b0  = (const float*)d_in[5];
    const float* g0  = (const float*)d_in[6];
    const float* be0 = (const float*)d_in[7];
    const float* W1  = (const float*)d_in[8];
    const float* b1  = (const float*)d_in[9];
    const float* g1  = (const float*)d_in[10];
    const float* be1 = (const float*)d_in[11];
    float* out = (float*)d_out;

    char* ws = (char*)d_ws;
    // [Xb2 16MB][y0 32MB][y1 32MB; fT (8MB) + G (8MB) alias y1 (dead before gemm1)]
    unsigned short* Xb2 = (unsigned short*)ws;
    unsigned short* y0  = (unsigned short*)(ws + ((size_t)16 << 20));
    unsigned short* y1  = (unsigned short*)(ws + ((size_t)48 << 20));
    unsigned short* fT  = (unsigned short*)(ws + ((size_t)48 << 20));   // 8 MB
    unsigned short* G   = (unsigned short*)(ws + ((size_t)56 << 20));   // 8 MB
    char* tail          = ws + ((size_t)80 << 20);
    int*    idx   = (int*)tail;                       // 768 KB
    float*  wgt   = (float*)(tail + 786432);          // 768 KB
    float4* cand4 = (float4*)(tail + 2 * 786432);     // 256 KB
    unsigned short* Wb1 = (unsigned short*)(tail + 2 * 786432 + 262144);  // 128 KB
    unsigned short* Wa  = Wb1 + CO * K1;              // 128 KB
    unsigned short* Wlo = Wa + CO * CHH;              // 64 KB
    char* tail2   = (char*)(Wlo + CO * CL);
    float* psumT0 = (float*)tail2;                    // 1 MB  [256][1024]
    float* psqT0  = psumT0 + 256 * 1024;              // 1 MB
    float* psumT1 = psqT0 + 256 * 1024;               // 1 MB
    float* psqT1  = psumT1 + 256 * 1024;              // 1 MB
    float* prm    = psqT1 + 256 * 1024;
    float* scale0 = prm,        *shift0 = prm + 256;
    float* scale1 = prm + 512,  *shift1 = prm + 768;

    k_setup<<<(CO * K0 + 255) / 256, 256, 0, stream>>>(W0, Wa, Wlo, W1, Wb1,
                                                       xyz_high, cand4);
    k_transpose_fh<<<dim3(NH / 32, CHH / 32, BB), 256, 0, stream>>>(feat_high, fT);
    // G[b][j][m] = sum_c W0a[m][c] * fT[b][j][c]   (tiny GEMM, 256 blocks)
    k_gemm97<CHH, 8, false, false, false, false><<<256, 256, 0, stream>>>(
        fT, Wa, nullptr, nullptr, nullptr, nullptr, nullptr, nullptr,
        G, nullptr, nullptr);
    k_knn<<<dim3(NL / 64, BB), 256, 0, stream>>>(xyz_low, cand4, idx, wgt);
    k_fl_t<<<dim3(NL / 64, CL / 32, BB), 256, 0, stream>>>(feat_low, Xb2);

    // y0 = W0lo * feat_lowT (+ bias0 + gathered interp of G) + stats
    k_gemm97<CL, 32, true, false, true, true><<<1024, 256, 0, stream>>>(
        Xb2, Wlo, b0, nullptr, nullptr, G, idx, wgt, y0, psumT0, psqT0);
    k_fin<<<256, 256, 0, stream>>>(psumT0, psqT0, g0, be0, scale0, shift0);
    // y1 = W1 * relu(BN0(y0)) + bias1 + stats
    k_gemm97<K1, 32, true, true, false, true><<<1024, 256, 0, stream>>>(
        y0, Wb1, b1, scale0, shift0, nullptr, nullptr, nullptr, y1, psumT1, psqT1);
    k_fin<<<256, 256, 0, stream>>>(psumT1, psqT1, g1, be1, scale1, shift1);
    k_out<<<dim3(NL / 64, CO / 64, BB), 256, 0, stream>>>(y1, scale1, shift1, out);
}

// Round 17
// 146.723 us; speedup vs baseline: 1.1819x; 1.1819x over previous
//
#include <hip/hip_runtime.h>
#include <math.h>

#define BB 16
#define NL 4096
#define NH 1024
#define CL 128
#define CHH 256
#define K0 384
#define K1 256
#define CO 256
#define BN_EPS 1e-5f

typedef __attribute__((ext_vector_type(8))) short bfrag;     // 8 bf16
typedef __attribute__((ext_vector_type(4))) float f32x4;
typedef __attribute__((ext_vector_type(4))) unsigned short ushort4b;

__device__ inline unsigned short f2bf(float f) {
    unsigned int u = __builtin_bit_cast(unsigned int, f);
    u += 0x7fffu + ((u >> 16) & 1u);                 // RNE
    return (unsigned short)(u >> 16);
}
__device__ inline float bf2f(unsigned short h) {
    unsigned int u = ((unsigned int)h) << 16;
    return __builtin_bit_cast(float, u);
}

// ---------------------------------------------------------------------------
// setup: weights f32->bf16 + candidate packing (one launch)
// ---------------------------------------------------------------------------
__global__ __launch_bounds__(256) void k_setup(const float* __restrict__ W0s,
                                               unsigned short* __restrict__ Wb0,
                                               const float* __restrict__ W1s,
                                               unsigned short* __restrict__ Wb1,
                                               const float* __restrict__ xyzh,
                                               float4* __restrict__ cand4) {
    int i = blockIdx.x * 256 + threadIdx.x;
    if (i < CO * K0) Wb0[i] = f2bf(W0s[i]);
    if (i < CO * K1) Wb1[i] = f2bf(W1s[i]);
    if (i < BB * NH) {
        float x = xyzh[3 * i], y = xyzh[3 * i + 1], z = xyzh[3 * i + 2];
        float ss = __fadd_rn(__fadd_rn(__fmul_rn(x, x), __fmul_rn(y, y)),
                             __fmul_rn(z, z));
        cand4[i] = make_float4(x, y, z, ss);
    }
}

// ---------------------------------------------------------------------------
// transpose feat_high (B, CH, NH) f32 -> fT (B, NH, CH) bf16
// ---------------------------------------------------------------------------
__global__ __launch_bounds__(256) void k_transpose_fh(const float* __restrict__ fh,
                                                      unsigned short* __restrict__ fT) {
    __shared__ float s[32][33];
    int b = blockIdx.z;
    int c0 = blockIdx.y * 32;
    int m0 = blockIdx.x * 32;
    int tx = threadIdx.x % 32, ty = threadIdx.x / 32;
    const float* src = fh + (size_t)b * CHH * NH;
    unsigned short* dst = fT + (size_t)b * NH * CHH;
#pragma unroll
    for (int j = 0; j < 4; j++)
        s[ty + 8 * j][tx] = src[(size_t)(c0 + ty + 8 * j) * NH + m0 + tx];
    __syncthreads();
    int mi = threadIdx.x >> 3;
    int cp = threadIdx.x & 7;
#pragma unroll
    for (int h = 0; h < 2; h++) {
        int ci = (cp + 8 * h) * 2;
        unsigned int o = (unsigned int)f2bf(s[ci][mi]) |
                         ((unsigned int)f2bf(s[ci + 1][mi]) << 16);
        *(unsigned int*)&dst[(size_t)(m0 + mi) * CHH + c0 + ci] = o;
    }
}

// ---------------------------------------------------------------------------
// 3-NN search v7: wave = segment, broadcast LDS reads (conflict-free).
// ---------------------------------------------------------------------------
__global__ __launch_bounds__(256) void k_knn(const float* __restrict__ xyzl,
                                             const float4* __restrict__ cand4,
                                             int* __restrict__ idx,
                                             float* __restrict__ wgt) {
    __shared__ float4 cnd[NH];
    __shared__ float tls[4][64][3];
    __shared__ int   ils[4][64][3];

    int b = blockIdx.y;
    for (int p = threadIdx.x; p < NH; p += 256)
        cnd[p] = cand4[(size_t)b * NH + p];
    __syncthreads();

    int lane = threadIdx.x & 63;
    int w = threadIdx.x >> 6;
    int n = blockIdx.x * 64 + lane;

    const float* xl = xyzl + ((size_t)b * NL + n) * 3;
    float l0 = xl[0], l1 = xl[1], l2 = xl[2];
    float a = __fadd_rn(__fadd_rn(__fmul_rn(l0, l0), __fmul_rn(l1, l1)),
                        __fmul_rn(l2, l2));

    float t0 = INFINITY, t1 = INFINITY, t2 = INFINITY;
    int i0 = 0, i1 = 0, i2 = 0;
    int mb = w * 256;
#pragma unroll 8
    for (int j = 0; j < 256; j++) {
        float4 c = cnd[mb + j];
        int m = mb + j;
        float dot = __fadd_rn(__fadd_rn(__fmul_rn(l0, c.x), __fmul_rn(l1, c.y)),
                              __fmul_rn(l2, c.z));
        float dd = __fsub_rn(__fadd_rn(a, c.w), __fmul_rn(2.0f, dot));
        bool c0 = dd < t0, c1 = dd < t1, c2 = dd < t2;
        float nt0 = fminf(dd, t0);
        float nt1 = __builtin_amdgcn_fmed3f(dd, t0, t1);
        float nt2 = __builtin_amdgcn_fmed3f(dd, t1, t2);
        i2 = c1 ? i1 : (c2 ? m : i2);
        i1 = c0 ? i0 : (c1 ? m : i1);
        i0 = c0 ? m : i0;
        t0 = nt0; t1 = nt1; t2 = nt2;
    }
    tls[w][lane][0] = t0; tls[w][lane][1] = t1; tls[w][lane][2] = t2;
    ils[w][lane][0] = i0; ils[w][lane][1] = i1; ils[w][lane][2] = i2;
    __syncthreads();

    if (threadIdx.x < 64) {
        int p = threadIdx.x;
        float u0 = tls[0][p][0], u1 = tls[0][p][1], u2 = tls[0][p][2];
        int   j0 = ils[0][p][0], j1 = ils[0][p][1], j2 = ils[0][p][2];
#pragma unroll
        for (int sg = 1; sg < 4; sg++) {
#pragma unroll
            for (int e = 0; e < 3; e++) {
                float dd = tls[sg][p][e];
                int m = ils[sg][p][e];
                bool c0 = dd < u0, c1 = dd < u1, c2 = dd < u2;
                u2 = c1 ? u1 : (c2 ? dd : u2);
                j2 = c1 ? j1 : (c2 ? m : j2);
                u1 = c0 ? u0 : (c1 ? dd : u1);
                j1 = c0 ? j0 : (c1 ? m : j1);
                u0 = c0 ? dd : u0;
                j0 = c0 ? m : j0;
            }
        }
        u0 = fmaxf(u0, 0.0f); u1 = fmaxf(u1, 0.0f); u2 = fmaxf(u2, 0.0f);
        float d0 = sqrtf(u0), d1 = sqrtf(u1), d2 = sqrtf(u2);
        float w0 = 1.0f / fmaxf(d0, 1e-8f);
        float w1 = 1.0f / fmaxf(d1, 1e-8f);
        float w2 = 1.0f / fmaxf(d2, 1e-8f);
        float wsum = __fadd_rn(__fadd_rn(w0, w1), w2);
        w0 /= wsum; w1 /= wsum; w2 /= wsum;
        int nn = blockIdx.x * 64 + p;
        size_t base = ((size_t)b * NL + nn) * 3;
        idx[base] = j0; idx[base + 1] = j1; idx[base + 2] = j2;
        wgt[base] = w0; wgt[base + 1] = w1; wgt[base + 2] = w2;
    }
}

// ---------------------------------------------------------------------------
// feat_low (B, CL, NL) f32 -> Xb2[b][n][c] bf16, c in [0,128) (slim layout)
// ---------------------------------------------------------------------------
__global__ __launch_bounds__(256) void k_fl_t(const float* __restrict__ fl,
                                              unsigned short* __restrict__ Xb2) {
    __shared__ unsigned short s[32][68];
    int b = blockIdx.z, c0 = blockIdx.y * 32, n0 = blockIdx.x * 64;
    int tx = threadIdx.x & 63, ty = threadIdx.x >> 6;
    const float* src = fl + ((size_t)b * CL + c0) * NL + n0;
#pragma unroll
    for (int i = 0; i < 8; i++) {
        int c = ty * 8 + i;
        s[c][tx] = f2bf(src[(size_t)c * NL + tx]);
    }
    __syncthreads();
    int n = threadIdx.x >> 2, q = threadIdx.x & 3;
    ushort4b o0, o1;
#pragma unroll
    for (int e = 0; e < 4; e++) o0[e] = s[q * 8 + e][n];
#pragma unroll
    for (int e = 0; e < 4; e++) o1[e] = s[q * 8 + 4 + e][n];
    unsigned short* dst = Xb2 + ((size_t)b * NL + n0 + n) * CL + c0 + q * 8;
    *(ushort4b*)dst = o0;
    *(ushort4b*)(dst + 4) = o1;
}

// ---------------------------------------------------------------------------
// staging transforms (bit-identical chains)
// ---------------------------------------------------------------------------
__device__ inline bfrag bnrelu8(bfrag v, f32x4 s0, f32x4 s1, f32x4 h0, f32x4 h1) {
    bfrag o;
#pragma unroll
    for (int e = 0; e < 4; e++)
        o[e] = (short)f2bf(fmaxf(fmaf(s0[e], bf2f((unsigned short)v[e]), h0[e]), 0.f));
#pragma unroll
    for (int e = 0; e < 4; e++)
        o[4 + e] = (short)f2bf(fmaxf(fmaf(s1[e], bf2f((unsigned short)v[4 + e]), h1[e]), 0.f));
    return o;
}

__device__ inline bfrag interp8(bfrag f0, bfrag f1, bfrag f2,
                                float w0, float w1, float w2) {
    bfrag o;
#pragma unroll
    for (int e = 0; e < 8; e++) {
        float f = __fadd_rn(__fadd_rn(__fmul_rn(w0, bf2f((unsigned short)f0[e])),
                                      __fmul_rn(w1, bf2f((unsigned short)f1[e]))),
                            __fmul_rn(w2, bf2f((unsigned short)f2[e])));
        o[e] = (short)f2bf(f);
    }
    return o;
}

// ---------------------------------------------------------------------------
// Fused MFMA GEMM (R12, best-known): BM=256, BN=128, BK=32, 512 thr / 8 waves,
// XOR-swizzled dbuf LDS. INTERP fused on B staging (exact chains); BN fused
// on gemm1 staging. Epilogue: reg stats to distinct slots + LDS-transposed
// coalesced Y store. XCD-aware 1-D grid (512).
// ---------------------------------------------------------------------------
__device__ inline int swz(int r, int cb) {
    return r * 32 + ((cb ^ ((r >> 1) & 3)) << 3);   // short index, 16B blocks
}

#define EROW 264   // epilogue LDS row stride in shorts (528B, 16B-aligned)

template <int K, bool INTERP, bool BN>
__global__ __launch_bounds__(512) void k_gemmf(const unsigned short* __restrict__ X,
                                               const unsigned short* __restrict__ fT,
                                               const int* __restrict__ idx,
                                               const float* __restrict__ wgt,
                                               const unsigned short* __restrict__ Wb,
                                               const float* __restrict__ bias,
                                               const float* __restrict__ bnsc,
                                               const float* __restrict__ bnsh,
                                               unsigned short* __restrict__ Y,
                                               float* __restrict__ psumT,
                                               float* __restrict__ psqT) {
    __shared__ __align__(16) unsigned short smem[2 * 256 * 32 + 2 * 128 * 32];
    unsigned short (*sA)[256 * 32] = (unsigned short (*)[256 * 32])smem;
    unsigned short (*sB)[128 * 32] = (unsigned short (*)[128 * 32])(smem + 2 * 256 * 32);
    unsigned short* sE = smem;            // epilogue overlay: 64*EROW shorts

    int bt = blockIdx.x;              // 0..511
    int xcd = bt & 7, ii = bt >> 3;   // ii: 0..63 within XCD
    int b  = xcd * 2 + (ii >> 5);     // 2 batches per XCD
    int n0 = (ii & 31) * 128;

    int tid = threadIdx.x;
    int lane = tid & 63;
    int wid = tid >> 6;               // 0..7
    int wm = wid >> 1, wn = wid & 1;  // 4 x 2 waves of 64x64

    int sr = tid >> 2;                // 0..127
    int scb = tid & 3;                // 16B block within BK row
    int swA0 = swz(sr, scb), swA1 = swz(sr + 128, scb);
    int swB = swz(sr, scb);

    const unsigned short* Wt = Wb + scb * 8;
    int nrow = n0 + sr;

    // per-thread interp metadata (hoisted once)
    const unsigned short* fTb;
    int ba0 = 0, ba1 = 0, ba2 = 0;
    float iw0 = 0.f, iw1 = 0.f, iw2 = 0.f;
    if (INTERP) {
        size_t ib = ((size_t)b * NL + nrow) * 3;
        ba0 = idx[ib] * CHH; ba1 = idx[ib + 1] * CHH; ba2 = idx[ib + 2] * CHH;
        iw0 = wgt[ib]; iw1 = wgt[ib + 1]; iw2 = wgt[ib + 2];
        fTb = fT + (size_t)b * NH * CHH;
    }
    const unsigned short* Xrow =
        X + ((size_t)b * NL + nrow) * (INTERP ? CL : CO);

    f32x4 acc[4][4] = {};

    auto stageB = [&](int tt, bfrag& r0, bfrag& r1, bfrag& r2) {
        int cg = tt * 32 + scb * 8;
        if (INTERP) {
            if (cg < CHH) {
                r0 = *(const bfrag*)&fTb[ba0 + cg];
                r1 = *(const bfrag*)&fTb[ba1 + cg];
                r2 = *(const bfrag*)&fTb[ba2 + cg];
            } else {
                r0 = *(const bfrag*)&Xrow[cg - CHH];
            }
        } else {
            r0 = *(const bfrag*)&Xrow[cg];
        }
    };
    auto combineB = [&](int tt, bfrag r0, bfrag r1, bfrag r2) -> bfrag {
        int cg = tt * 32 + scb * 8;
        if (INTERP) {
            if (cg < CHH) return interp8(r0, r1, r2, iw0, iw1, iw2);
            return r0;
        }
        if (BN) {
            f32x4 sc0 = *(const f32x4*)&bnsc[cg], sc1 = *(const f32x4*)&bnsc[cg + 4];
            f32x4 sh0 = *(const f32x4*)&bnsh[cg], sh1 = *(const f32x4*)&bnsh[cg + 4];
            return bnrelu8(r0, sc0, sc1, sh0, sh1);
        }
        return r0;
    };

    // prologue: tile 0
    {
        bfrag a0 = *(const bfrag*)&Wt[(size_t)sr * K];
        bfrag a1 = *(const bfrag*)&Wt[(size_t)(sr + 128) * K];
        bfrag r0, r1, r2;
        stageB(0, r0, r1, r2);
        bfrag bb = combineB(0, r0, r1, r2);
        *(bfrag*)&sA[0][swA0] = a0;
        *(bfrag*)&sA[0][swA1] = a1;
        *(bfrag*)&sB[0][swB] = bb;
    }
    __syncthreads();

    const int nkt = K / 32;
    int cur = 0;
#pragma unroll 2
    for (int tt = 0; tt < nkt; tt++) {
        bfrag na0, na1, r0, r1, r2;
        bool more = (tt + 1 < nkt);
        if (more) {
            int kk = (tt + 1) * 32;
            na0 = *(const bfrag*)&Wt[(size_t)sr * K + kk];
            na1 = *(const bfrag*)&Wt[(size_t)(sr + 128) * K + kk];
            stageB(tt + 1, r0, r1, r2);
        }
        bfrag af[4], bf[4];
#pragma unroll
        for (int mi = 0; mi < 4; mi++) {
            int r = wm * 64 + mi * 16 + (lane & 15);
            af[mi] = *(const bfrag*)&sA[cur][swz(r, lane >> 4)];
        }
#pragma unroll
        for (int ni = 0; ni < 4; ni++) {
            int r = wn * 64 + ni * 16 + (lane & 15);
            bf[ni] = *(const bfrag*)&sB[cur][swz(r, lane >> 4)];
        }
#pragma unroll
        for (int mi = 0; mi < 4; mi++)
#pragma unroll
            for (int ni = 0; ni < 4; ni++)
                acc[mi][ni] = __builtin_amdgcn_mfma_f32_16x16x32_bf16(
                    af[mi], bf[ni], acc[mi][ni], 0, 0, 0);
        if (more) {
            bfrag nb = combineB(tt + 1, r0, r1, r2);
            *(bfrag*)&sA[cur ^ 1][swA0] = na0;
            *(bfrag*)&sA[cur ^ 1][swA1] = na1;
            *(bfrag*)&sB[cur ^ 1][swB] = nb;
            __syncthreads();
            cur ^= 1;
        }
    }

    __syncthreads();                       // retire sA/sB before overlay reuse

    // stats from registers (pre-rounding f32 values = c + bias)
    int col = lane & 15, rg = (lane >> 4) << 2;
    int slot = bt * 2 + wn;
#pragma unroll
    for (int mi = 0; mi < 4; mi++) {
        int m = wm * 64 + mi * 16 + rg;
        f32x4 bv = *(const f32x4*)&bias[m];
        f32x4 sacc = {0.f, 0.f, 0.f, 0.f}, qacc = {0.f, 0.f, 0.f, 0.f};
#pragma unroll
        for (int ni = 0; ni < 4; ni++) {
            f32x4 c = acc[mi][ni];
#pragma unroll
            for (int j = 0; j < 4; j++) {
                float sv = c[j] + bv[j];
                sacc[j] += sv;
                qacc[j] += sv * sv;
            }
        }
#pragma unroll
        for (int j = 0; j < 4; j++) {
            float s = sacc[j], q = qacc[j];
#pragma unroll
            for (int off = 1; off < 16; off <<= 1) {
                s += __shfl_xor(s, off, 64);
                q += __shfl_xor(q, off, 64);
            }
            if (col == 0) {
                psumT[(size_t)(m + j) * 1024 + slot] = s;
                psqT[(size_t)(m + j) * 1024 + slot] = q;
            }
        }
    }

    // two-half LDS transpose + fully-coalesced Y stores
#pragma unroll
    for (int half = 0; half < 2; half++) {
        if (wn == half) {
#pragma unroll
            for (int mi = 0; mi < 4; mi++) {
                int m = wm * 64 + mi * 16 + rg;
                f32x4 bv = *(const f32x4*)&bias[m];
#pragma unroll
                for (int ni = 0; ni < 4; ni++) {
                    int nloc = ni * 16 + col;
                    f32x4 c = acc[mi][ni];
                    ushort4b o;
                    o[0] = f2bf(c[0] + bv[0]); o[1] = f2bf(c[1] + bv[1]);
                    o[2] = f2bf(c[2] + bv[2]); o[3] = f2bf(c[3] + bv[3]);
                    *(ushort4b*)&sE[nloc * EROW + m] = o;
                }
            }
        }
        __syncthreads();
#pragma unroll
        for (int s2 = 0; s2 < 4; s2++) {
            int row = s2 * 16 + (tid >> 5);
            int ch = tid & 31;
            *(bfrag*)&Y[((size_t)b * NL + n0 + half * 64 + row) * CO + ch * 8] =
                *(const bfrag*)&sE[row * EROW + ch * 8];
        }
        __syncthreads();
    }
}

// ---------------------------------------------------------------------------
// reduce per-block partials -> scale/shift. One block per channel.
// ---------------------------------------------------------------------------
__global__ __launch_bounds__(256) void k_fin(const float* __restrict__ psumT,
                                             const float* __restrict__ psqT,
                                             const float* __restrict__ gamma,
                                             const float* __restrict__ beta,
                                             float* __restrict__ scale,
                                             float* __restrict__ shift) {
    int c = blockIdx.x;
    const float* ps = psumT + (size_t)c * 1024;
    const float* pq = psqT + (size_t)c * 1024;
    float s = 0.f, q = 0.f;
    for (int i = threadIdx.x; i < 1024; i += 256) { s += ps[i]; q += pq[i]; }
#pragma unroll
    for (int off = 1; off < 64; off <<= 1) {
        s += __shfl_xor(s, off, 64);
        q += __shfl_xor(q, off, 64);
    }
    __shared__ float ls[4], lq[4];
    if ((threadIdx.x & 63) == 0) { ls[threadIdx.x >> 6] = s; lq[threadIdx.x >> 6] = q; }
    __syncthreads();
    if (threadIdx.x == 0) {
        float S = ls[0] + ls[1] + ls[2] + ls[3];
        float Q = lq[0] + lq[1] + lq[2] + lq[3];
        float N = (float)(BB * NL);
        float mean = S / N;
        float var = Q / N - mean * mean;
        float sc = gamma[c] / sqrtf(var + BN_EPS);
        scale[c] = sc;
        shift[c] = beta[c] - mean * sc;
    }
}

// ---------------------------------------------------------------------------
// final: read y1 bf16 [b][n][m], BN1+ReLU, transpose-write f32 out [b][m][n]
// ---------------------------------------------------------------------------
__global__ __launch_bounds__(256) void k_out(const unsigned short* __restrict__ y1,
                                             const float* __restrict__ scale,
                                             const float* __restrict__ shift,
                                             float* __restrict__ out) {
    __shared__ float s[64][65];
    int b = blockIdx.z, m0 = blockIdx.y * 64, n0 = blockIdx.x * 64;
    int r = threadIdx.x >> 3;
    int mq = (threadIdx.x & 7) * 8;
#pragma unroll
    for (int it = 0; it < 2; it++) {
        int row = r + it * 32;
        bfrag v = *(const bfrag*)&y1[((size_t)b * NL + n0 + row) * CO + m0 + mq];
#pragma unroll
        for (int e = 0; e < 8; e++) {
            int m = mq + e;
            float f = bf2f((unsigned short)v[e]);
            s[m][row] = fmaxf(fmaf(scale[m0 + m], f, shift[m0 + m]), 0.f);
        }
    }
    __syncthreads();
    int ch = threadIdx.x & 15;
    int mb4 = threadIdx.x >> 4;
#pragma unroll
    for (int it = 0; it < 4; it++) {
        int m = it * 16 + mb4;
        float4 v = make_float4(s[m][ch * 4], s[m][ch * 4 + 1],
                               s[m][ch * 4 + 2], s[m][ch * 4 + 3]);
        *(float4*)&out[((size_t)b * CO + m0 + m) * NL + n0 + ch * 4] = v;
    }
}

// ---------------------------------------------------------------------------
extern "C" void kernel_launch(void* const* d_in, const int* in_sizes, int n_in,
                              void* d_out, int out_size, void* d_ws, size_t ws_size,
                              hipStream_t stream) {
    const float* xyz_low   = (const float*)d_in[0];
    const float* xyz_high  = (const float*)d_in[1];
    const float* feat_low  = (const float*)d_in[2];
    const float* feat_high = (const float*)d_in[3];
    const float* W0  = (const float*)d_in[4];
    const float* b0  = (const float*)d_in[5];
    const float* g0  = (const float*)d_in[6];
    const float* be0 = (const float*)d_in[7];
    const float* W1  = (const float*)d_in[8];
    const float* b1  = (const float*)d_in[9];
    const float* g1  = (const float*)d_in[10];
    const float* be1 = (const float*)d_in[11];
    float* out = (float*)d_out;

    char* ws = (char*)d_ws;
    // [Xb2 16MB][y0 32MB][y1 32MB (fT 8MB aliases start; dead before gemm1)]
    unsigned short* Xb2 = (unsigned short*)ws;
    unsigned short* y0  = (unsigned short*)(ws + ((size_t)16 << 20));
    unsigned short* y1  = (unsigned short*)(ws + ((size_t)48 << 20));
    unsigned short* fT  = (unsigned short*)(ws + ((size_t)48 << 20));
    char* tail          = ws + ((size_t)80 << 20);
    int*    idx   = (int*)tail;                       // 768 KB
    float*  wgt   = (float*)(tail + 786432);          // 768 KB
    float4* cand4 = (float4*)(tail + 2 * 786432);     // 256 KB
    unsigned short* Wb0 = (unsigned short*)(tail + 2 * 786432 + 262144);
    unsigned short* Wb1 = Wb0 + CO * K0;              // +192 KB
    char* tail2   = (char*)(Wb1 + CO * K1);           // +128 KB
    float* psumT0 = (float*)tail2;                    // 1 MB  [256][1024]
    float* psqT0  = psumT0 + 256 * 1024;              // 1 MB
    float* psumT1 = psqT0 + 256 * 1024;               // 1 MB
    float* psqT1  = psumT1 + 256 * 1024;              // 1 MB
    float* prm    = psqT1 + 256 * 1024;
    float* scale0 = prm,        *shift0 = prm + 256;
    float* scale1 = prm + 512,  *shift1 = prm + 768;

    k_setup<<<(CO * K0 + 255) / 256, 256, 0, stream>>>(W0, Wb0, W1, Wb1,
                                                       xyz_high, cand4);
    k_transpose_fh<<<dim3(NH / 32, CHH / 32, BB), 256, 0, stream>>>(feat_high, fT);
    k_knn<<<dim3(NL / 64, BB), 256, 0, stream>>>(xyz_low, cand4, idx, wgt);
    k_fl_t<<<dim3(NL / 64, CL / 32, BB), 256, 0, stream>>>(feat_low, Xb2);

    k_gemmf<K0, true, false><<<512, 512, 0, stream>>>(
        Xb2, fT, idx, wgt, Wb0, b0, nullptr, nullptr, y0, psumT0, psqT0);
    k_fin<<<256, 256, 0, stream>>>(psumT0, psqT0, g0, be0, scale0, shift0);
    k_gemmf<K1, false, true><<<512, 512, 0, stream>>>(
        y0, nullptr, nullptr, nullptr, Wb1, b1, scale0, shift0, y1, psumT1, psqT1);
    k_fin<<<256, 256, 0, stream>>>(psumT1, psqT1, g1, be1, scale1, shift1);
    k_out<<<dim3(NL / 64, CO / 64, BB), 256, 0, stream>>>(y1, scale1, shift1, out);
}

// Round 19
// 129.457 us; speedup vs baseline: 1.3395x; 1.1334x over previous
//
#include <hip/hip_runtime.h>
#include <math.h>

#define BB 16
#define NL 4096
#define NH 1024
#define CL 128
#define CHH 256
#define K0 384
#define K1 256
#define CO 256
#define BN_EPS 1e-5f

typedef __attribute__((ext_vector_type(8))) short bfrag;     // 8 bf16
typedef __attribute__((ext_vector_type(4))) float f32x4;
typedef __attribute__((ext_vector_type(4))) unsigned short ushort4b;

__device__ inline unsigned short f2bf(float f) {
    unsigned int u = __builtin_bit_cast(unsigned int, f);
    u += 0x7fffu + ((u >> 16) & 1u);                 // RNE
    return (unsigned short)(u >> 16);
}
__device__ inline float bf2f(unsigned short h) {
    unsigned int u = ((unsigned int)h) << 16;
    return __builtin_bit_cast(float, u);
}

// ---------------------------------------------------------------------------
// FRONT fat kernel: grid partitioned into independent segments so the
// VALU-bound knn blocks co-schedule with the memory-bound transpose/convert
// blocks on the same CUs (single launch; no inter-part dependencies).
//   [0, 1024)          : 3-NN search (candidate ss computed inline, exact
//                        __f*_rn chain == old k_prep -> bit-identical idx/wgt)
//   [1024, 5120)       : feat_high transpose -> fT bf16
//   [5120, 9216)       : feat_low transpose-convert -> Xb2 bf16
//   [9216, 9600)       : W0/W1 f32 -> bf16
// Shared memory: raw byte arena, per-segment structs cast onto it.
// ---------------------------------------------------------------------------
#define KNN_BLKS   1024
#define TR_BLKS    4096
#define FLT_BLKS   4096
#define CVT_BLKS   384

struct SMknn { float4 cnd[NH]; float tls[4][64][3]; int ils[4][64][3]; };
struct SMtr  { float s[32][33]; };
struct SMflt { unsigned short s[32][68]; };

__global__ __launch_bounds__(256) void k_front(const float* __restrict__ xyzl,
                                               const float* __restrict__ xyzh,
                                               const float* __restrict__ fh,
                                               const float* __restrict__ fl,
                                               const float* __restrict__ W0s,
                                               const float* __restrict__ W1s,
                                               unsigned short* __restrict__ Wb0,
                                               unsigned short* __restrict__ Wb1,
                                               unsigned short* __restrict__ fT,
                                               unsigned short* __restrict__ Xb2,
                                               int* __restrict__ idx,
                                               float* __restrict__ wgt) {
    __shared__ __align__(16) char smem_raw[sizeof(SMknn)];   // 22528 B (max)

    int blk = blockIdx.x;

    if (blk < KNN_BLKS) {
        // ---------------- 3-NN search (v7 logic, inline ss) ----------------
        SMknn& sm = *(SMknn*)smem_raw;
        int b = blk >> 6;
        int nb = blk & 63;
        const float* xh = xyzh + (size_t)b * NH * 3;
        for (int p = threadIdx.x; p < NH; p += 256) {
            const float* xp = xh + 3 * p;
            float x = xp[0], y = xp[1], z = xp[2];
            float ss = __fadd_rn(__fadd_rn(__fmul_rn(x, x), __fmul_rn(y, y)),
                                 __fmul_rn(z, z));
            sm.cnd[p] = make_float4(x, y, z, ss);
        }
        __syncthreads();

        int lane = threadIdx.x & 63;
        int w = threadIdx.x >> 6;
        int n = nb * 64 + lane;

        const float* xl = xyzl + ((size_t)b * NL + n) * 3;
        float l0 = xl[0], l1 = xl[1], l2 = xl[2];
        float a = __fadd_rn(__fadd_rn(__fmul_rn(l0, l0), __fmul_rn(l1, l1)),
                            __fmul_rn(l2, l2));

        float t0 = INFINITY, t1 = INFINITY, t2 = INFINITY;
        int i0 = 0, i1 = 0, i2 = 0;
        int mb = w * 256;
#pragma unroll 8
        for (int j = 0; j < 256; j++) {
            float4 c = sm.cnd[mb + j];
            int m = mb + j;
            float dot = __fadd_rn(__fadd_rn(__fmul_rn(l0, c.x), __fmul_rn(l1, c.y)),
                                  __fmul_rn(l2, c.z));
            float dd = __fsub_rn(__fadd_rn(a, c.w), __fmul_rn(2.0f, dot));
            bool c0 = dd < t0, c1 = dd < t1, c2 = dd < t2;
            float nt0 = fminf(dd, t0);
            float nt1 = __builtin_amdgcn_fmed3f(dd, t0, t1);
            float nt2 = __builtin_amdgcn_fmed3f(dd, t1, t2);
            i2 = c1 ? i1 : (c2 ? m : i2);
            i1 = c0 ? i0 : (c1 ? m : i1);
            i0 = c0 ? m : i0;
            t0 = nt0; t1 = nt1; t2 = nt2;
        }
        sm.tls[w][lane][0] = t0; sm.tls[w][lane][1] = t1; sm.tls[w][lane][2] = t2;
        sm.ils[w][lane][0] = i0; sm.ils[w][lane][1] = i1; sm.ils[w][lane][2] = i2;
        __syncthreads();

        if (threadIdx.x < 64) {
            int p = threadIdx.x;
            float u0 = sm.tls[0][p][0], u1 = sm.tls[0][p][1], u2 = sm.tls[0][p][2];
            int   j0 = sm.ils[0][p][0], j1 = sm.ils[0][p][1], j2 = sm.ils[0][p][2];
#pragma unroll
            for (int sg = 1; sg < 4; sg++) {
#pragma unroll
                for (int e = 0; e < 3; e++) {
                    float dd = sm.tls[sg][p][e];
                    int m = sm.ils[sg][p][e];
                    bool c0 = dd < u0, c1 = dd < u1, c2 = dd < u2;
                    u2 = c1 ? u1 : (c2 ? dd : u2);
                    j2 = c1 ? j1 : (c2 ? m : j2);
                    u1 = c0 ? u0 : (c1 ? dd : u1);
                    j1 = c0 ? j0 : (c1 ? m : j1);
                    u0 = c0 ? dd : u0;
                    j0 = c0 ? m : j0;
                }
            }
            u0 = fmaxf(u0, 0.0f); u1 = fmaxf(u1, 0.0f); u2 = fmaxf(u2, 0.0f);
            float d0 = sqrtf(u0), d1 = sqrtf(u1), d2 = sqrtf(u2);
            float w0 = 1.0f / fmaxf(d0, 1e-8f);
            float w1 = 1.0f / fmaxf(d1, 1e-8f);
            float w2 = 1.0f / fmaxf(d2, 1e-8f);
            float wsum = __fadd_rn(__fadd_rn(w0, w1), w2);
            w0 /= wsum; w1 /= wsum; w2 /= wsum;
            int nn = nb * 64 + p;
            size_t base = ((size_t)b * NL + nn) * 3;
            idx[base] = j0; idx[base + 1] = j1; idx[base + 2] = j2;
            wgt[base] = w0; wgt[base + 1] = w1; wgt[base + 2] = w2;
        }
        return;
    }

    if (blk < KNN_BLKS + TR_BLKS) {
        // ---------------- feat_high transpose -> fT bf16 --------------------
        SMtr& sm = *(SMtr*)smem_raw;
        int t = blk - KNN_BLKS;              // 32 x 8 x 16
        int m0 = (t & 31) * 32;
        int c0 = ((t >> 5) & 7) * 32;
        int b  = t >> 8;
        int tx = threadIdx.x % 32, ty = threadIdx.x / 32;
        const float* src = fh + (size_t)b * CHH * NH;
        unsigned short* dst = fT + (size_t)b * NH * CHH;
#pragma unroll
        for (int j = 0; j < 4; j++)
            sm.s[ty + 8 * j][tx] = src[(size_t)(c0 + ty + 8 * j) * NH + m0 + tx];
        __syncthreads();
        int mi = threadIdx.x >> 3;
        int cp = threadIdx.x & 7;
#pragma unroll
        for (int h = 0; h < 2; h++) {
            int ci = (cp + 8 * h) * 2;
            unsigned int o = (unsigned int)f2bf(sm.s[ci][mi]) |
                             ((unsigned int)f2bf(sm.s[ci + 1][mi]) << 16);
            *(unsigned int*)&dst[(size_t)(m0 + mi) * CHH + c0 + ci] = o;
        }
        return;
    }

    if (blk < KNN_BLKS + TR_BLKS + FLT_BLKS) {
        // ---------------- feat_low transpose-convert -> Xb2 -----------------
        SMflt& sm = *(SMflt*)smem_raw;
        int t = blk - (KNN_BLKS + TR_BLKS);  // 64 x 4 x 16
        int n0 = (t & 63) * 64;
        int c0 = ((t >> 6) & 3) * 32;
        int b  = t >> 8;
        int tx = threadIdx.x & 63, ty = threadIdx.x >> 6;
        const float* src = fl + ((size_t)b * CL + c0) * NL + n0;
#pragma unroll
        for (int i = 0; i < 8; i++) {
            int c = ty * 8 + i;
            sm.s[c][tx] = f2bf(src[(size_t)c * NL + tx]);
        }
        __syncthreads();
        int n = threadIdx.x >> 2, q = threadIdx.x & 3;
        ushort4b o0, o1;
#pragma unroll
        for (int e = 0; e < 4; e++) o0[e] = sm.s[q * 8 + e][n];
#pragma unroll
        for (int e = 0; e < 4; e++) o1[e] = sm.s[q * 8 + 4 + e][n];
        unsigned short* dst = Xb2 + ((size_t)b * NL + n0 + n) * CL + c0 + q * 8;
        *(ushort4b*)dst = o0;
        *(ushort4b*)(dst + 4) = o1;
        return;
    }

    // ---------------- weight conversion -------------------------------------
    {
        int i = (blk - (KNN_BLKS + TR_BLKS + FLT_BLKS)) * 256 + threadIdx.x;
        if (i < CO * K0) Wb0[i] = f2bf(W0s[i]);
        if (i < CO * K1) Wb1[i] = f2bf(W1s[i]);
    }
}

// ---------------------------------------------------------------------------
// staging transforms (bit-identical chains)
// ---------------------------------------------------------------------------
__device__ inline bfrag bnrelu8(bfrag v, f32x4 s0, f32x4 s1, f32x4 h0, f32x4 h1) {
    bfrag o;
#pragma unroll
    for (int e = 0; e < 4; e++)
        o[e] = (short)f2bf(fmaxf(fmaf(s0[e], bf2f((unsigned short)v[e]), h0[e]), 0.f));
#pragma unroll
    for (int e = 0; e < 4; e++)
        o[4 + e] = (short)f2bf(fmaxf(fmaf(s1[e], bf2f((unsigned short)v[4 + e]), h1[e]), 0.f));
    return o;
}

__device__ inline bfrag interp8(bfrag f0, bfrag f1, bfrag f2,
                                float w0, float w1, float w2) {
    bfrag o;
#pragma unroll
    for (int e = 0; e < 8; e++) {
        float f = __fadd_rn(__fadd_rn(__fmul_rn(w0, bf2f((unsigned short)f0[e])),
                                      __fmul_rn(w1, bf2f((unsigned short)f1[e]))),
                            __fmul_rn(w2, bf2f((unsigned short)f2[e])));
        o[e] = (short)f2bf(f);
    }
    return o;
}

// ---------------------------------------------------------------------------
// Fused MFMA GEMM (R12/R17 best-known): BM=256, BN=128, BK=32, 512 thr /
// 8 waves, XOR-swizzled dbuf LDS. INTERP fused on B staging; BN fused on
// gemm1 staging. Epilogue: reg stats to distinct slots + LDS-transposed
// coalesced Y store. XCD-aware 1-D grid (512).
// ---------------------------------------------------------------------------
__device__ inline int swz(int r, int cb) {
    return r * 32 + ((cb ^ ((r >> 1) & 3)) << 3);   // short index, 16B blocks
}

#define EROW 264   // epilogue LDS row stride in shorts (528B, 16B-aligned)

template <int K, bool INTERP, bool BN>
__global__ __launch_bounds__(512) void k_gemmf(const unsigned short* __restrict__ X,
                                               const unsigned short* __restrict__ fT,
                                               const int* __restrict__ idx,
                                               const float* __restrict__ wgt,
                                               const unsigned short* __restrict__ Wb,
                                               const float* __restrict__ bias,
                                               const float* __restrict__ bnsc,
                                               const float* __restrict__ bnsh,
                                               unsigned short* __restrict__ Y,
                                               float* __restrict__ psumT,
                                               float* __restrict__ psqT) {
    __shared__ __align__(16) unsigned short smem[2 * 256 * 32 + 2 * 128 * 32];
    unsigned short (*sA)[256 * 32] = (unsigned short (*)[256 * 32])smem;
    unsigned short (*sB)[128 * 32] = (unsigned short (*)[128 * 32])(smem + 2 * 256 * 32);
    unsigned short* sE = smem;            // epilogue overlay: 64*EROW shorts

    int bt = blockIdx.x;              // 0..511
    int xcd = bt & 7, ii = bt >> 3;   // ii: 0..63 within XCD
    int b  = xcd * 2 + (ii >> 5);     // 2 batches per XCD
    int n0 = (ii & 31) * 128;

    int tid = threadIdx.x;
    int lane = tid & 63;
    int wid = tid >> 6;               // 0..7
    int wm = wid >> 1, wn = wid & 1;  // 4 x 2 waves of 64x64

    int sr = tid >> 2;                // 0..127
    int scb = tid & 3;                // 16B block within BK row
    int swA0 = swz(sr, scb), swA1 = swz(sr + 128, scb);
    int swB = swz(sr, scb);

    const unsigned short* Wt = Wb + scb * 8;
    int nrow = n0 + sr;

    // per-thread interp metadata (hoisted once)
    const unsigned short* fTb;
    int ba0 = 0, ba1 = 0, ba2 = 0;
    float iw0 = 0.f, iw1 = 0.f, iw2 = 0.f;
    if (INTERP) {
        size_t ib = ((size_t)b * NL + nrow) * 3;
        ba0 = idx[ib] * CHH; ba1 = idx[ib + 1] * CHH; ba2 = idx[ib + 2] * CHH;
        iw0 = wgt[ib]; iw1 = wgt[ib + 1]; iw2 = wgt[ib + 2];
        fTb = fT + (size_t)b * NH * CHH;
    }
    const unsigned short* Xrow =
        X + ((size_t)b * NL + nrow) * (INTERP ? CL : CO);

    f32x4 acc[4][4] = {};

    auto stageB = [&](int tt, bfrag& r0, bfrag& r1, bfrag& r2) {
        int cg = tt * 32 + scb * 8;
        if (INTERP) {
            if (cg < CHH) {
                r0 = *(const bfrag*)&fTb[ba0 + cg];
                r1 = *(const bfrag*)&fTb[ba1 + cg];
                r2 = *(const bfrag*)&fTb[ba2 + cg];
            } else {
                r0 = *(const bfrag*)&Xrow[cg - CHH];
            }
        } else {
            r0 = *(const bfrag*)&Xrow[cg];
        }
    };
    auto combineB = [&](int tt, bfrag r0, bfrag r1, bfrag r2) -> bfrag {
        int cg = tt * 32 + scb * 8;
        if (INTERP) {
            if (cg < CHH) return interp8(r0, r1, r2, iw0, iw1, iw2);
            return r0;
        }
        if (BN) {
            f32x4 sc0 = *(const f32x4*)&bnsc[cg], sc1 = *(const f32x4*)&bnsc[cg + 4];
            f32x4 sh0 = *(const f32x4*)&bnsh[cg], sh1 = *(const f32x4*)&bnsh[cg + 4];
            return bnrelu8(r0, sc0, sc1, sh0, sh1);
        }
        return r0;
    };

    // prologue: tile 0
    {
        bfrag a0 = *(const bfrag*)&Wt[(size_t)sr * K];
        bfrag a1 = *(const bfrag*)&Wt[(size_t)(sr + 128) * K];
        bfrag r0, r1, r2;
        stageB(0, r0, r1, r2);
        bfrag bb = combineB(0, r0, r1, r2);
        *(bfrag*)&sA[0][swA0] = a0;
        *(bfrag*)&sA[0][swA1] = a1;
        *(bfrag*)&sB[0][swB] = bb;
    }
    __syncthreads();

    const int nkt = K / 32;
    int cur = 0;
#pragma unroll 2
    for (int tt = 0; tt < nkt; tt++) {
        bfrag na0, na1, r0, r1, r2;
        bool more = (tt + 1 < nkt);
        if (more) {
            int kk = (tt + 1) * 32;
            na0 = *(const bfrag*)&Wt[(size_t)sr * K + kk];
            na1 = *(const bfrag*)&Wt[(size_t)(sr + 128) * K + kk];
            stageB(tt + 1, r0, r1, r2);
        }
        bfrag af[4], bf[4];
#pragma unroll
        for (int mi = 0; mi < 4; mi++) {
            int r = wm * 64 + mi * 16 + (lane & 15);
            af[mi] = *(const bfrag*)&sA[cur][swz(r, lane >> 4)];
        }
#pragma unroll
        for (int ni = 0; ni < 4; ni++) {
            int r = wn * 64 + ni * 16 + (lane & 15);
            bf[ni] = *(const bfrag*)&sB[cur][swz(r, lane >> 4)];
        }
#pragma unroll
        for (int mi = 0; mi < 4; mi++)
#pragma unroll
            for (int ni = 0; ni < 4; ni++)
                acc[mi][ni] = __builtin_amdgcn_mfma_f32_16x16x32_bf16(
                    af[mi], bf[ni], acc[mi][ni], 0, 0, 0);
        if (more) {
            bfrag nb = combineB(tt + 1, r0, r1, r2);
            *(bfrag*)&sA[cur ^ 1][swA0] = na0;
            *(bfrag*)&sA[cur ^ 1][swA1] = na1;
            *(bfrag*)&sB[cur ^ 1][swB] = nb;
            __syncthreads();
            cur ^= 1;
        }
    }

    __syncthreads();                       // retire sA/sB before overlay reuse

    // stats from registers (pre-rounding f32 values = c + bias)
    int col = lane & 15, rg = (lane >> 4) << 2;
    int slot = bt * 2 + wn;
#pragma unroll
    for (int mi = 0; mi < 4; mi++) {
        int m = wm * 64 + mi * 16 + rg;
        f32x4 bv = *(const f32x4*)&bias[m];
        f32x4 sacc = {0.f, 0.f, 0.f, 0.f}, qacc = {0.f, 0.f, 0.f, 0.f};
#pragma unroll
        for (int ni = 0; ni < 4; ni++) {
            f32x4 c = acc[mi][ni];
#pragma unroll
            for (int j = 0; j < 4; j++) {
                float sv = c[j] + bv[j];
                sacc[j] += sv;
                qacc[j] += sv * sv;
            }
        }
#pragma unroll
        for (int j = 0; j < 4; j++) {
            float s = sacc[j], q = qacc[j];
#pragma unroll
            for (int off = 1; off < 16; off <<= 1) {
                s += __shfl_xor(s, off, 64);
                q += __shfl_xor(q, off, 64);
            }
            if (col == 0) {
                psumT[(size_t)(m + j) * 1024 + slot] = s;
                psqT[(size_t)(m + j) * 1024 + slot] = q;
            }
        }
    }

    // two-half LDS transpose + fully-coalesced Y stores
#pragma unroll
    for (int half = 0; half < 2; half++) {
        if (wn == half) {
#pragma unroll
            for (int mi = 0; mi < 4; mi++) {
                int m = wm * 64 + mi * 16 + rg;
                f32x4 bv = *(const f32x4*)&bias[m];
#pragma unroll
                for (int ni = 0; ni < 4; ni++) {
                    int nloc = ni * 16 + col;
                    f32x4 c = acc[mi][ni];
                    ushort4b o;
                    o[0] = f2bf(c[0] + bv[0]); o[1] = f2bf(c[1] + bv[1]);
                    o[2] = f2bf(c[2] + bv[2]); o[3] = f2bf(c[3] + bv[3]);
                    *(ushort4b*)&sE[nloc * EROW + m] = o;
                }
            }
        }
        __syncthreads();
#pragma unroll
        for (int s2 = 0; s2 < 4; s2++) {
            int row = s2 * 16 + (tid >> 5);
            int ch = tid & 31;
            *(bfrag*)&Y[((size_t)b * NL + n0 + half * 64 + row) * CO + ch * 8] =
                *(const bfrag*)&sE[row * EROW + ch * 8];
        }
        __syncthreads();
    }
}

// ---------------------------------------------------------------------------
// reduce per-block partials -> scale/shift. One block per channel.
// ---------------------------------------------------------------------------
__global__ __launch_bounds__(256) void k_fin(const float* __restrict__ psumT,
                                             const float* __restrict__ psqT,
                                             const float* __restrict__ gamma,
                                             const float* __restrict__ beta,
                                             float* __restrict__ scale,
                                             float* __restrict__ shift) {
    int c = blockIdx.x;
    const float* ps = psumT + (size_t)c * 1024;
    const float* pq = psqT + (size_t)c * 1024;
    float s = 0.f, q = 0.f;
    for (int i = threadIdx.x; i < 1024; i += 256) { s += ps[i]; q += pq[i]; }
#pragma unroll
    for (int off = 1; off < 64; off <<= 1) {
        s += __shfl_xor(s, off, 64);
        q += __shfl_xor(q, off, 64);
    }
    __shared__ float ls[4], lq[4];
    if ((threadIdx.x & 63) == 0) { ls[threadIdx.x >> 6] = s; lq[threadIdx.x >> 6] = q; }
    __syncthreads();
    if (threadIdx.x == 0) {
        float S = ls[0] + ls[1] + ls[2] + ls[3];
        float Q = lq[0] + lq[1] + lq[2] + lq[3];
        float N = (float)(BB * NL);
        float mean = S / N;
        float var = Q / N - mean * mean;
        float sc = gamma[c] / sqrtf(var + BN_EPS);
        scale[c] = sc;
        shift[c] = beta[c] - mean * sc;
    }
}

// ---------------------------------------------------------------------------
// final: read y1 bf16 [b][n][m], BN1+ReLU, transpose-write f32 out [b][m][n]
// ---------------------------------------------------------------------------
__global__ __launch_bounds__(256) void k_out(const unsigned short* __restrict__ y1,
                                             const float* __restrict__ scale,
                                             const float* __restrict__ shift,
                                             float* __restrict__ out) {
    __shared__ float s[64][65];
    int b = blockIdx.z, m0 = blockIdx.y * 64, n0 = blockIdx.x * 64;
    int r = threadIdx.x >> 3;
    int mq = (threadIdx.x & 7) * 8;
#pragma unroll
    for (int it = 0; it < 2; it++) {
        int row = r + it * 32;
        bfrag v = *(const bfrag*)&y1[((size_t)b * NL + n0 + row) * CO + m0 + mq];
#pragma unroll
        for (int e = 0; e < 8; e++) {
            int m = mq + e;
            float f = bf2f((unsigned short)v[e]);
            s[m][row] = fmaxf(fmaf(scale[m0 + m], f, shift[m0 + m]), 0.f);
        }
    }
    __syncthreads();
    int ch = threadIdx.x & 15;
    int mb4 = threadIdx.x >> 4;
#pragma unroll
    for (int it = 0; it < 4; it++) {
        int m = it * 16 + mb4;
        float4 v = make_float4(s[m][ch * 4], s[m][ch * 4 + 1],
                               s[m][ch * 4 + 2], s[m][ch * 4 + 3]);
        *(float4*)&out[((size_t)b * CO + m0 + m) * NL + n0 + ch * 4] = v;
    }
}

// ---------------------------------------------------------------------------
extern "C" void kernel_launch(void* const* d_in, const int* in_sizes, int n_in,
                              void* d_out, int out_size, void* d_ws, size_t ws_size,
                              hipStream_t stream) {
    const float* xyz_low   = (const float*)d_in[0];
    const float* xyz_high  = (const float*)d_in[1];
    const float* feat_low  = (const float*)d_in[2];
    const float* feat_high = (const float*)d_in[3];
    const float* W0  = (const float*)d_in[4];
    const float* b0  = (const float*)d_in[5];
    const float* g0  = (const float*)d_in[6];
    const float* be0 = (const float*)d_in[7];
    const float* W1  = (const float*)d_in[8];
    const float* b1  = (const float*)d_in[9];
    const float* g1  = (const float*)d_in[10];
    const float* be1 = (const float*)d_in[11];
    float* out = (float*)d_out;

    char* ws = (char*)d_ws;
    // [Xb2 16MB][y0 32MB][y1 32MB (fT 8MB aliases start; dead before gemm1)]
    unsigned short* Xb2 = (unsigned short*)ws;
    unsigned short* y0  = (unsigned short*)(ws + ((size_t)16 << 20));
    unsigned short* y1  = (unsigned short*)(ws + ((size_t)48 << 20));
    unsigned short* fT  = (unsigned short*)(ws + ((size_t)48 << 20));
    char* tail          = ws + ((size_t)80 << 20);
    int*    idx   = (int*)tail;                       // 768 KB
    float*  wgt   = (float*)(tail + 786432);          // 768 KB
    unsigned short* Wb0 = (unsigned short*)(tail + 2 * 786432);
    unsigned short* Wb1 = Wb0 + CO * K0;              // +192 KB
    char* tail2   = (char*)(Wb1 + CO * K1);           // +128 KB
    float* psumT0 = (float*)tail2;                    // 1 MB  [256][1024]
    float* psqT0  = psumT0 + 256 * 1024;              // 1 MB
    float* psumT1 = psqT0 + 256 * 1024;               // 1 MB
    float* psqT1  = psumT1 + 256 * 1024;              // 1 MB
    float* prm    = psqT1 + 256 * 1024;
    float* scale0 = prm,        *shift0 = prm + 256;
    float* scale1 = prm + 512,  *shift1 = prm + 768;

    k_front<<<KNN_BLKS + TR_BLKS + FLT_BLKS + CVT_BLKS, 256, 0, stream>>>(
        xyz_low, xyz_high, feat_high, feat_low, W0, W1,
        Wb0, Wb1, fT, Xb2, idx, wgt);

    k_gemmf<K0, true, false><<<512, 512, 0, stream>>>(
        Xb2, fT, idx, wgt, Wb0, b0, nullptr, nullptr, y0, psumT0, psqT0);
    k_fin<<<256, 256, 0, stream>>>(psumT0, psqT0, g0, be0, scale0, shift0);
    k_gemmf<K1, false, true><<<512, 512, 0, stream>>>(
        y0, nullptr, nullptr, nullptr, Wb1, b1, scale0, shift0, y1, psumT1, psqT1);
    k_fin<<<256, 256, 0, stream>>>(psumT1, psqT1, g1, be1, scale1, shift1);
    k_out<<<dim3(NL / 64, CO / 64, BB), 256, 0, stream>>>(y1, scale1, shift1, out);
}

// Round 20
// 127.040 us; speedup vs baseline: 1.3650x; 1.0190x over previous
//
#include <hip/hip_runtime.h>
#include <math.h>

#define BB 16
#define NL 4096
#define NH 1024
#define CL 128
#define CHH 256
#define K0 384
#define K1 256
#define CO 256
#define BN_EPS 1e-5f

typedef __attribute__((ext_vector_type(8))) short bfrag;     // 8 bf16
typedef __attribute__((ext_vector_type(4))) float f32x4;
typedef __attribute__((ext_vector_type(4))) unsigned short ushort4b;

__device__ inline unsigned short f2bf(float f) {
    unsigned int u = __builtin_bit_cast(unsigned int, f);
    u += 0x7fffu + ((u >> 16) & 1u);                 // RNE
    return (unsigned short)(u >> 16);
}
__device__ inline float bf2f(unsigned short h) {
    unsigned int u = ((unsigned int)h) << 16;
    return __builtin_bit_cast(float, u);
}

// ---------------------------------------------------------------------------
// FRONT fat kernel: grid partitioned into independent segments so the
// VALU-bound knn blocks co-schedule with the memory-bound transpose/convert
// blocks on the same CUs (single launch; no inter-part dependencies).
//   [0, 512)           : 3-NN search, 2 points/lane (two independent top-3
//                        chains -> ILP hides the med3 serial latency);
//                        broadcast LDS reads; exact __f*_rn chains; stable
//                        segment merge -> idx/wgt bit-identical to R19.
//   [512, 4608)        : feat_high transpose -> fT bf16
//   [4608, 8704)       : feat_low transpose-convert -> Xb2 bf16
//   [8704, 9088)       : W0/W1 f32 -> bf16
// ---------------------------------------------------------------------------
#define KNN_BLKS   512
#define TR_BLKS    4096
#define FLT_BLKS   4096
#define CVT_BLKS   384

struct SMknn { float4 cnd[NH]; float tls[4][128][3]; int ils[4][128][3]; };
struct SMtr  { float s[32][33]; };
struct SMflt { unsigned short s[32][68]; };

__global__ __launch_bounds__(256) void k_front(const float* __restrict__ xyzl,
                                               const float* __restrict__ xyzh,
                                               const float* __restrict__ fh,
                                               const float* __restrict__ fl,
                                               const float* __restrict__ W0s,
                                               const float* __restrict__ W1s,
                                               unsigned short* __restrict__ Wb0,
                                               unsigned short* __restrict__ Wb1,
                                               unsigned short* __restrict__ fT,
                                               unsigned short* __restrict__ Xb2,
                                               int* __restrict__ idx,
                                               float* __restrict__ wgt) {
    __shared__ __align__(16) char smem_raw[sizeof(SMknn)];   // 28672 B (max)

    int blk = blockIdx.x;

    if (blk < KNN_BLKS) {
        // -------- 3-NN search: 2 points/lane, broadcast reads, med3 --------
        SMknn& sm = *(SMknn*)smem_raw;
        int b  = blk >> 5;                 // 32 blocks per batch
        int nb = blk & 31;                 // 128 points per block
        const float* xh = xyzh + (size_t)b * NH * 3;
        for (int p = threadIdx.x; p < NH; p += 256) {
            const float* xp = xh + 3 * p;
            float x = xp[0], y = xp[1], z = xp[2];
            float ss = __fadd_rn(__fadd_rn(__fmul_rn(x, x), __fmul_rn(y, y)),
                                 __fmul_rn(z, z));
            sm.cnd[p] = make_float4(x, y, z, ss);
        }
        __syncthreads();

        int lane = threadIdx.x & 63;
        int w = threadIdx.x >> 6;          // segment
        int nA = nb * 128 + lane;
        int nB = nA + 64;

        const float* xa = xyzl + ((size_t)b * NL + nA) * 3;
        const float* xb = xyzl + ((size_t)b * NL + nB) * 3;
        float a0 = xa[0], a1 = xa[1], a2 = xa[2];
        float e0 = xb[0], e1 = xb[1], e2 = xb[2];
        float aa = __fadd_rn(__fadd_rn(__fmul_rn(a0, a0), __fmul_rn(a1, a1)),
                             __fmul_rn(a2, a2));
        float ae = __fadd_rn(__fadd_rn(__fmul_rn(e0, e0), __fmul_rn(e1, e1)),
                             __fmul_rn(e2, e2));

        float ta0 = INFINITY, ta1 = INFINITY, ta2 = INFINITY;
        float tb0 = INFINITY, tb1 = INFINITY, tb2 = INFINITY;
        int ia0 = 0, ia1 = 0, ia2 = 0, ib0 = 0, ib1 = 0, ib2 = 0;
        int mb = w * 256;
#pragma unroll 4
        for (int j = 0; j < 256; j++) {
            float4 c = sm.cnd[mb + j];     // broadcast read feeds both points
            int m = mb + j;
            {
                float dot = __fadd_rn(__fadd_rn(__fmul_rn(a0, c.x), __fmul_rn(a1, c.y)),
                                      __fmul_rn(a2, c.z));
                float dd = __fsub_rn(__fadd_rn(aa, c.w), __fmul_rn(2.0f, dot));
                bool c0 = dd < ta0, c1 = dd < ta1, c2 = dd < ta2;
                float nt0 = fminf(dd, ta0);
                float nt1 = __builtin_amdgcn_fmed3f(dd, ta0, ta1);
                float nt2 = __builtin_amdgcn_fmed3f(dd, ta1, ta2);
                ia2 = c1 ? ia1 : (c2 ? m : ia2);
                ia1 = c0 ? ia0 : (c1 ? m : ia1);
                ia0 = c0 ? m : ia0;
                ta0 = nt0; ta1 = nt1; ta2 = nt2;
            }
            {
                float dot = __fadd_rn(__fadd_rn(__fmul_rn(e0, c.x), __fmul_rn(e1, c.y)),
                                      __fmul_rn(e2, c.z));
                float dd = __fsub_rn(__fadd_rn(ae, c.w), __fmul_rn(2.0f, dot));
                bool c0 = dd < tb0, c1 = dd < tb1, c2 = dd < tb2;
                float nt0 = fminf(dd, tb0);
                float nt1 = __builtin_amdgcn_fmed3f(dd, tb0, tb1);
                float nt2 = __builtin_amdgcn_fmed3f(dd, tb1, tb2);
                ib2 = c1 ? ib1 : (c2 ? m : ib2);
                ib1 = c0 ? ib0 : (c1 ? m : ib1);
                ib0 = c0 ? m : ib0;
                tb0 = nt0; tb1 = nt1; tb2 = nt2;
            }
        }
        sm.tls[w][lane][0] = ta0; sm.tls[w][lane][1] = ta1; sm.tls[w][lane][2] = ta2;
        sm.ils[w][lane][0] = ia0; sm.ils[w][lane][1] = ia1; sm.ils[w][lane][2] = ia2;
        sm.tls[w][lane + 64][0] = tb0; sm.tls[w][lane + 64][1] = tb1;
        sm.tls[w][lane + 64][2] = tb2;
        sm.ils[w][lane + 64][0] = ib0; sm.ils[w][lane + 64][1] = ib1;
        sm.ils[w][lane + 64][2] = ib2;
        __syncthreads();

        if (threadIdx.x < 128) {
            int p = threadIdx.x;
            float u0 = sm.tls[0][p][0], u1 = sm.tls[0][p][1], u2 = sm.tls[0][p][2];
            int   j0 = sm.ils[0][p][0], j1 = sm.ils[0][p][1], j2 = sm.ils[0][p][2];
#pragma unroll
            for (int sg = 1; sg < 4; sg++) {
#pragma unroll
                for (int e = 0; e < 3; e++) {
                    float dd = sm.tls[sg][p][e];
                    int m = sm.ils[sg][p][e];
                    bool c0 = dd < u0, c1 = dd < u1, c2 = dd < u2;
                    u2 = c1 ? u1 : (c2 ? dd : u2);
                    j2 = c1 ? j1 : (c2 ? m : j2);
                    u1 = c0 ? u0 : (c1 ? dd : u1);
                    j1 = c0 ? j0 : (c1 ? m : j1);
                    u0 = c0 ? dd : u0;
                    j0 = c0 ? m : j0;
                }
            }
            u0 = fmaxf(u0, 0.0f); u1 = fmaxf(u1, 0.0f); u2 = fmaxf(u2, 0.0f);
            float d0 = sqrtf(u0), d1 = sqrtf(u1), d2 = sqrtf(u2);
            float w0 = 1.0f / fmaxf(d0, 1e-8f);
            float w1 = 1.0f / fmaxf(d1, 1e-8f);
            float w2 = 1.0f / fmaxf(d2, 1e-8f);
            float wsum = __fadd_rn(__fadd_rn(w0, w1), w2);
            w0 /= wsum; w1 /= wsum; w2 /= wsum;
            int nn = nb * 128 + p;
            size_t base = ((size_t)b * NL + nn) * 3;
            idx[base] = j0; idx[base + 1] = j1; idx[base + 2] = j2;
            wgt[base] = w0; wgt[base + 1] = w1; wgt[base + 2] = w2;
        }
        return;
    }

    if (blk < KNN_BLKS + TR_BLKS) {
        // ---------------- feat_high transpose -> fT bf16 --------------------
        SMtr& sm = *(SMtr*)smem_raw;
        int t = blk - KNN_BLKS;              // 32 x 8 x 16
        int m0 = (t & 31) * 32;
        int c0 = ((t >> 5) & 7) * 32;
        int b  = t >> 8;
        int tx = threadIdx.x % 32, ty = threadIdx.x / 32;
        const float* src = fh + (size_t)b * CHH * NH;
        unsigned short* dst = fT + (size_t)b * NH * CHH;
#pragma unroll
        for (int j = 0; j < 4; j++)
            sm.s[ty + 8 * j][tx] = src[(size_t)(c0 + ty + 8 * j) * NH + m0 + tx];
        __syncthreads();
        int mi = threadIdx.x >> 3;
        int cp = threadIdx.x & 7;
#pragma unroll
        for (int h = 0; h < 2; h++) {
            int ci = (cp + 8 * h) * 2;
            unsigned int o = (unsigned int)f2bf(sm.s[ci][mi]) |
                             ((unsigned int)f2bf(sm.s[ci + 1][mi]) << 16);
            *(unsigned int*)&dst[(size_t)(m0 + mi) * CHH + c0 + ci] = o;
        }
        return;
    }

    if (blk < KNN_BLKS + TR_BLKS + FLT_BLKS) {
        // ---------------- feat_low transpose-convert -> Xb2 -----------------
        SMflt& sm = *(SMflt*)smem_raw;
        int t = blk - (KNN_BLKS + TR_BLKS);  // 64 x 4 x 16
        int n0 = (t & 63) * 64;
        int c0 = ((t >> 6) & 3) * 32;
        int b  = t >> 8;
        int tx = threadIdx.x & 63, ty = threadIdx.x >> 6;
        const float* src = fl + ((size_t)b * CL + c0) * NL + n0;
#pragma unroll
        for (int i = 0; i < 8; i++) {
            int c = ty * 8 + i;
            sm.s[c][tx] = f2bf(src[(size_t)c * NL + tx]);
        }
        __syncthreads();
        int n = threadIdx.x >> 2, q = threadIdx.x & 3;
        ushort4b o0, o1;
#pragma unroll
        for (int e = 0; e < 4; e++) o0[e] = sm.s[q * 8 + e][n];
#pragma unroll
        for (int e = 0; e < 4; e++) o1[e] = sm.s[q * 8 + 4 + e][n];
        unsigned short* dst = Xb2 + ((size_t)b * NL + n0 + n) * CL + c0 + q * 8;
        *(ushort4b*)dst = o0;
        *(ushort4b*)(dst + 4) = o1;
        return;
    }

    // ---------------- weight conversion -------------------------------------
    {
        int i = (blk - (KNN_BLKS + TR_BLKS + FLT_BLKS)) * 256 + threadIdx.x;
        if (i < CO * K0) Wb0[i] = f2bf(W0s[i]);
        if (i < CO * K1) Wb1[i] = f2bf(W1s[i]);
    }
}

// ---------------------------------------------------------------------------
// staging transforms (bit-identical chains)
// ---------------------------------------------------------------------------
__device__ inline bfrag bnrelu8(bfrag v, f32x4 s0, f32x4 s1, f32x4 h0, f32x4 h1) {
    bfrag o;
#pragma unroll
    for (int e = 0; e < 4; e++)
        o[e] = (short)f2bf(fmaxf(fmaf(s0[e], bf2f((unsigned short)v[e]), h0[e]), 0.f));
#pragma unroll
    for (int e = 0; e < 4; e++)
        o[4 + e] = (short)f2bf(fmaxf(fmaf(s1[e], bf2f((unsigned short)v[4 + e]), h1[e]), 0.f));
    return o;
}

__device__ inline bfrag interp8(bfrag f0, bfrag f1, bfrag f2,
                                float w0, float w1, float w2) {
    bfrag o;
#pragma unroll
    for (int e = 0; e < 8; e++) {
        float f = __fadd_rn(__fadd_rn(__fmul_rn(w0, bf2f((unsigned short)f0[e])),
                                      __fmul_rn(w1, bf2f((unsigned short)f1[e]))),
                            __fmul_rn(w2, bf2f((unsigned short)f2[e])));
        o[e] = (short)f2bf(f);
    }
    return o;
}

// ---------------------------------------------------------------------------
// Fused MFMA GEMM (R12/R17 best-known): BM=256, BN=128, BK=32, 512 thr /
// 8 waves, XOR-swizzled dbuf LDS. INTERP fused on B staging; BN fused on
// gemm1 staging. Epilogue: reg stats to distinct slots + LDS-transposed
// coalesced Y store. XCD-aware 1-D grid (512).
// ---------------------------------------------------------------------------
__device__ inline int swz(int r, int cb) {
    return r * 32 + ((cb ^ ((r >> 1) & 3)) << 3);   // short index, 16B blocks
}

#define EROW 264   // epilogue LDS row stride in shorts (528B, 16B-aligned)

template <int K, bool INTERP, bool BN>
__global__ __launch_bounds__(512) void k_gemmf(const unsigned short* __restrict__ X,
                                               const unsigned short* __restrict__ fT,
                                               const int* __restrict__ idx,
                                               const float* __restrict__ wgt,
                                               const unsigned short* __restrict__ Wb,
                                               const float* __restrict__ bias,
                                               const float* __restrict__ bnsc,
                                               const float* __restrict__ bnsh,
                                               unsigned short* __restrict__ Y,
                                               float* __restrict__ psumT,
                                               float* __restrict__ psqT) {
    __shared__ __align__(16) unsigned short smem[2 * 256 * 32 + 2 * 128 * 32];
    unsigned short (*sA)[256 * 32] = (unsigned short (*)[256 * 32])smem;
    unsigned short (*sB)[128 * 32] = (unsigned short (*)[128 * 32])(smem + 2 * 256 * 32);
    unsigned short* sE = smem;            // epilogue overlay: 64*EROW shorts

    int bt = blockIdx.x;              // 0..511
    int xcd = bt & 7, ii = bt >> 3;   // ii: 0..63 within XCD
    int b  = xcd * 2 + (ii >> 5);     // 2 batches per XCD
    int n0 = (ii & 31) * 128;

    int tid = threadIdx.x;
    int lane = tid & 63;
    int wid = tid >> 6;               // 0..7
    int wm = wid >> 1, wn = wid & 1;  // 4 x 2 waves of 64x64

    int sr = tid >> 2;                // 0..127
    int scb = tid & 3;                // 16B block within BK row
    int swA0 = swz(sr, scb), swA1 = swz(sr + 128, scb);
    int swB = swz(sr, scb);

    const unsigned short* Wt = Wb + scb * 8;
    int nrow = n0 + sr;

    // per-thread interp metadata (hoisted once)
    const unsigned short* fTb;
    int ba0 = 0, ba1 = 0, ba2 = 0;
    float iw0 = 0.f, iw1 = 0.f, iw2 = 0.f;
    if (INTERP) {
        size_t ib = ((size_t)b * NL + nrow) * 3;
        ba0 = idx[ib] * CHH; ba1 = idx[ib + 1] * CHH; ba2 = idx[ib + 2] * CHH;
        iw0 = wgt[ib]; iw1 = wgt[ib + 1]; iw2 = wgt[ib + 2];
        fTb = fT + (size_t)b * NH * CHH;
    }
    const unsigned short* Xrow =
        X + ((size_t)b * NL + nrow) * (INTERP ? CL : CO);

    f32x4 acc[4][4] = {};

    auto stageB = [&](int tt, bfrag& r0, bfrag& r1, bfrag& r2) {
        int cg = tt * 32 + scb * 8;
        if (INTERP) {
            if (cg < CHH) {
                r0 = *(const bfrag*)&fTb[ba0 + cg];
                r1 = *(const bfrag*)&fTb[ba1 + cg];
                r2 = *(const bfrag*)&fTb[ba2 + cg];
            } else {
                r0 = *(const bfrag*)&Xrow[cg - CHH];
            }
        } else {
            r0 = *(const bfrag*)&Xrow[cg];
        }
    };
    auto combineB = [&](int tt, bfrag r0, bfrag r1, bfrag r2) -> bfrag {
        int cg = tt * 32 + scb * 8;
        if (INTERP) {
            if (cg < CHH) return interp8(r0, r1, r2, iw0, iw1, iw2);
            return r0;
        }
        if (BN) {
            f32x4 sc0 = *(const f32x4*)&bnsc[cg], sc1 = *(const f32x4*)&bnsc[cg + 4];
            f32x4 sh0 = *(const f32x4*)&bnsh[cg], sh1 = *(const f32x4*)&bnsh[cg + 4];
            return bnrelu8(r0, sc0, sc1, sh0, sh1);
        }
        return r0;
    };

    // prologue: tile 0
    {
        bfrag a0 = *(const bfrag*)&Wt[(size_t)sr * K];
        bfrag a1 = *(const bfrag*)&Wt[(size_t)(sr + 128) * K];
        bfrag r0, r1, r2;
        stageB(0, r0, r1, r2);
        bfrag bb = combineB(0, r0, r1, r2);
        *(bfrag*)&sA[0][swA0] = a0;
        *(bfrag*)&sA[0][swA1] = a1;
        *(bfrag*)&sB[0][swB] = bb;
    }
    __syncthreads();

    const int nkt = K / 32;
    int cur = 0;
#pragma unroll 2
    for (int tt = 0; tt < nkt; tt++) {
        bfrag na0, na1, r0, r1, r2;
        bool more = (tt + 1 < nkt);
        if (more) {
            int kk = (tt + 1) * 32;
            na0 = *(const bfrag*)&Wt[(size_t)sr * K + kk];
            na1 = *(const bfrag*)&Wt[(size_t)(sr + 128) * K + kk];
            stageB(tt + 1, r0, r1, r2);
        }
        bfrag af[4], bf[4];
#pragma unroll
        for (int mi = 0; mi < 4; mi++) {
            int r = wm * 64 + mi * 16 + (lane & 15);
            af[mi] = *(const bfrag*)&sA[cur][swz(r, lane >> 4)];
        }
#pragma unroll
        for (int ni = 0; ni < 4; ni++) {
            int r = wn * 64 + ni * 16 + (lane & 15);
            bf[ni] = *(const bfrag*)&sB[cur][swz(r, lane >> 4)];
        }
#pragma unroll
        for (int mi = 0; mi < 4; mi++)
#pragma unroll
            for (int ni = 0; ni < 4; ni++)
                acc[mi][ni] = __builtin_amdgcn_mfma_f32_16x16x32_bf16(
                    af[mi], bf[ni], acc[mi][ni], 0, 0, 0);
        if (more) {
            bfrag nb = combineB(tt + 1, r0, r1, r2);
            *(bfrag*)&sA[cur ^ 1][swA0] = na0;
            *(bfrag*)&sA[cur ^ 1][swA1] = na1;
            *(bfrag*)&sB[cur ^ 1][swB] = nb;
            __syncthreads();
            cur ^= 1;
        }
    }

    __syncthreads();                       // retire sA/sB before overlay reuse

    // stats from registers (pre-rounding f32 values = c + bias)
    int col = lane & 15, rg = (lane >> 4) << 2;
    int slot = bt * 2 + wn;
#pragma unroll
    for (int mi = 0; mi < 4; mi++) {
        int m = wm * 64 + mi * 16 + rg;
        f32x4 bv = *(const f32x4*)&bias[m];
        f32x4 sacc = {0.f, 0.f, 0.f, 0.f}, qacc = {0.f, 0.f, 0.f, 0.f};
#pragma unroll
        for (int ni = 0; ni < 4; ni++) {
            f32x4 c = acc[mi][ni];
#pragma unroll
            for (int j = 0; j < 4; j++) {
                float sv = c[j] + bv[j];
                sacc[j] += sv;
                qacc[j] += sv * sv;
            }
        }
#pragma unroll
        for (int j = 0; j < 4; j++) {
            float s = sacc[j], q = qacc[j];
#pragma unroll
            for (int off = 1; off < 16; off <<= 1) {
                s += __shfl_xor(s, off, 64);
                q += __shfl_xor(q, off, 64);
            }
            if (col == 0) {
                psumT[(size_t)(m + j) * 1024 + slot] = s;
                psqT[(size_t)(m + j) * 1024 + slot] = q;
            }
        }
    }

    // two-half LDS transpose + fully-coalesced Y stores
#pragma unroll
    for (int half = 0; half < 2; half++) {
        if (wn == half) {
#pragma unroll
            for (int mi = 0; mi < 4; mi++) {
                int m = wm * 64 + mi * 16 + rg;
                f32x4 bv = *(const f32x4*)&bias[m];
#pragma unroll
                for (int ni = 0; ni < 4; ni++) {
                    int nloc = ni * 16 + col;
                    f32x4 c = acc[mi][ni];
                    ushort4b o;
                    o[0] = f2bf(c[0] + bv[0]); o[1] = f2bf(c[1] + bv[1]);
                    o[2] = f2bf(c[2] + bv[2]); o[3] = f2bf(c[3] + bv[3]);
                    *(ushort4b*)&sE[nloc * EROW + m] = o;
                }
            }
        }
        __syncthreads();
#pragma unroll
        for (int s2 = 0; s2 < 4; s2++) {
            int row = s2 * 16 + (tid >> 5);
            int ch = tid & 31;
            *(bfrag*)&Y[((size_t)b * NL + n0 + half * 64 + row) * CO + ch * 8] =
                *(const bfrag*)&sE[row * EROW + ch * 8];
        }
        __syncthreads();
    }
}

// ---------------------------------------------------------------------------
// reduce per-block partials -> scale/shift. One block per channel.
// ---------------------------------------------------------------------------
__global__ __launch_bounds__(256) void k_fin(const float* __restrict__ psumT,
                                             const float* __restrict__ psqT,
                                             const float* __restrict__ gamma,
                                             const float* __restrict__ beta,
                                             float* __restrict__ scale,
                                             float* __restrict__ shift) {
    int c = blockIdx.x;
    const float* ps = psumT + (size_t)c * 1024;
    const float* pq = psqT + (size_t)c * 1024;
    float s = 0.f, q = 0.f;
    for (int i = threadIdx.x; i < 1024; i += 256) { s += ps[i]; q += pq[i]; }
#pragma unroll
    for (int off = 1; off < 64; off <<= 1) {
        s += __shfl_xor(s, off, 64);
        q += __shfl_xor(q, off, 64);
    }
    __shared__ float ls[4], lq[4];
    if ((threadIdx.x & 63) == 0) { ls[threadIdx.x >> 6] = s; lq[threadIdx.x >> 6] = q; }
    __syncthreads();
    if (threadIdx.x == 0) {
        float S = ls[0] + ls[1] + ls[2] + ls[3];
        float Q = lq[0] + lq[1] + lq[2] + lq[3];
        float N = (float)(BB * NL);
        float mean = S / N;
        float var = Q / N - mean * mean;
        float sc = gamma[c] / sqrtf(var + BN_EPS);
        scale[c] = sc;
        shift[c] = beta[c] - mean * sc;
    }
}

// ---------------------------------------------------------------------------
// final: read y1 bf16 [b][n][m], BN1+ReLU, transpose-write f32 out [b][m][n]
// ---------------------------------------------------------------------------
__global__ __launch_bounds__(256) void k_out(const unsigned short* __restrict__ y1,
                                             const float* __restrict__ scale,
                                             const float* __restrict__ shift,
                                             float* __restrict__ out) {
    __shared__ float s[64][65];
    int b = blockIdx.z, m0 = blockIdx.y * 64, n0 = blockIdx.x * 64;
    int r = threadIdx.x >> 3;
    int mq = (threadIdx.x & 7) * 8;
#pragma unroll
    for (int it = 0; it < 2; it++) {
        int row = r + it * 32;
        bfrag v = *(const bfrag*)&y1[((size_t)b * NL + n0 + row) * CO + m0 + mq];
#pragma unroll
        for (int e = 0; e < 8; e++) {
            int m = mq + e;
            float f = bf2f((unsigned short)v[e]);
            s[m][row] = fmaxf(fmaf(scale[m0 + m], f, shift[m0 + m]), 0.f);
        }
    }
    __syncthreads();
    int ch = threadIdx.x & 15;
    int mb4 = threadIdx.x >> 4;
#pragma unroll
    for (int it = 0; it < 4; it++) {
        int m = it * 16 + mb4;
        float4 v = make_float4(s[m][ch * 4], s[m][ch * 4 + 1],
                               s[m][ch * 4 + 2], s[m][ch * 4 + 3]);
        *(float4*)&out[((size_t)b * CO + m0 + m) * NL + n0 + ch * 4] = v;
    }
}

// ---------------------------------------------------------------------------
extern "C" void kernel_launch(void* const* d_in, const int* in_sizes, int n_in,
                              void* d_out, int out_size, void* d_ws, size_t ws_size,
                              hipStream_t stream) {
    const float* xyz_low   = (const float*)d_in[0];
    const float* xyz_high  = (const float*)d_in[1];
    const float* feat_low  = (const float*)d_in[2];
    const float* feat_high = (const float*)d_in[3];
    const float* W0  = (const float*)d_in[4];
    const float* b0  = (const float*)d_in[5];
    const float* g0  = (const float*)d_in[6];
    const float* be0 = (const float*)d_in[7];
    const float* W1  = (const float*)d_in[8];
    const float* b1  = (const float*)d_in[9];
    const float* g1  = (const float*)d_in[10];
    const float* be1 = (const float*)d_in[11];
    float* out = (float*)d_out;

    char* ws = (char*)d_ws;
    // [Xb2 16MB][y0 32MB][y1 32MB (fT 8MB aliases start; dead before gemm1)]
    unsigned short* Xb2 = (unsigned short*)ws;
    unsigned short* y0  = (unsigned short*)(ws + ((size_t)16 << 20));
    unsigned short* y1  = (unsigned short*)(ws + ((size_t)48 << 20));
    unsigned short* fT  = (unsigned short*)(ws + ((size_t)48 << 20));
    char* tail          = ws + ((size_t)80 << 20);
    int*    idx   = (int*)tail;                       // 768 KB
    float*  wgt   = (float*)(tail + 786432);          // 768 KB
    unsigned short* Wb0 = (unsigned short*)(tail + 2 * 786432);
    unsigned short* Wb1 = Wb0 + CO * K0;              // +192 KB
    char* tail2   = (char*)(Wb1 + CO * K1);           // +128 KB
    float* psumT0 = (float*)tail2;                    // 1 MB  [256][1024]
    float* psqT0  = psumT0 + 256 * 1024;              // 1 MB
    float* psumT1 = psqT0 + 256 * 1024;               // 1 MB
    float* psqT1  = psumT1 + 256 * 1024;              // 1 MB
    float* prm    = psqT1 + 256 * 1024;
    float* scale0 = prm,        *shift0 = prm + 256;
    float* scale1 = prm + 512,  *shift1 = prm + 768;

    k_front<<<KNN_BLKS + TR_BLKS + FLT_BLKS + CVT_BLKS, 256, 0, stream>>>(
        xyz_low, xyz_high, feat_high, feat_low, W0, W1,
        Wb0, Wb1, fT, Xb2, idx, wgt);

    k_gemmf<K0, true, false><<<512, 512, 0, stream>>>(
        Xb2, fT, idx, wgt, Wb0, b0, nullptr, nullptr, y0, psumT0, psqT0);
    k_fin<<<256, 256, 0, stream>>>(psumT0, psqT0, g0, be0, scale0, shift0);
    k_gemmf<K1, false, true><<<512, 512, 0, stream>>>(
        y0, nullptr, nullptr, nullptr, Wb1, b1, scale0, shift0, y1, psumT1, psqT1);
    k_fin<<<256, 256, 0, stream>>>(psumT1, psqT1, g1, be1, scale1, shift1);
    k_out<<<dim3(NL / 64, CO / 64, BB), 256, 0, stream>>>(y1, scale1, shift1, out);
}